// Round 2
// baseline (403.038 us; speedup 1.0000x reference)
//
#include <hip/hip_runtime.h>
#include <hip/hip_fp16.h>
#include <math.h>

#define N_NODES 100000
#define N_EDGES 1600000
#define NH 4
#define HD 16
#define NB 98             // ceil(100000/1024) scan blocks
#define AGG_GROUPS 25000  // N_NODES/4
#define PT 128            // nodes per projection tile
#define NT 782            // ceil(100000/128)

typedef float fx4 __attribute__((ext_vector_type(4)));
typedef int   ix4 __attribute__((ext_vector_type(4)));

// ---- CSR build -------------------------------------------------------------

// off[] must be zeroed (hipMemsetAsync) before this
__global__ void hist_kernel(const int* __restrict__ dst_idx, int* __restrict__ off) {
    int tid = blockIdx.x * blockDim.x + threadIdx.x;
    int base = tid * 4;
    if (base + 3 < N_EDGES) {
        ix4 d = __builtin_nontemporal_load((const ix4*)dst_idx + tid);
        atomicAdd(&off[d.x], 1);
        atomicAdd(&off[d.y], 1);
        atomicAdd(&off[d.z], 1);
        atomicAdd(&off[d.w], 1);
    } else {
        for (int j = base; j < N_EDGES; j++) atomicAdd(&off[dst_idx[j]], 1);
    }
}

// per-block sums of 1024-element chunks
__global__ void scanA_kernel(const int* __restrict__ off, int* __restrict__ bsum) {
    __shared__ int s[256];
    int t = threadIdx.x;
    int base = blockIdx.x * 1024 + t * 4;
    int v = 0;
#pragma unroll
    for (int j = 0; j < 4; j++) {
        int idx = base + j;
        if (idx < N_NODES) v += off[idx];
    }
    s[t] = v;
    __syncthreads();
    for (int o = 128; o > 0; o >>= 1) {
        if (t < o) s[t] += s[t + o];
        __syncthreads();
    }
    if (t == 0) bsum[blockIdx.x] = s[0];
}

// in-place exclusive scan of counts -> offsets; copy to woff.
// Computes its own block-prefix from the raw bsum array (scanB folded in).
__global__ void scanC_kernel(int* __restrict__ off, const int* __restrict__ bsum,
                             int* __restrict__ woff) {
    __shared__ int sb[NB];
    __shared__ int s[256];
    int t = threadIdx.x;
    if (t < NB) sb[t] = bsum[t];
    __syncthreads();
    int pre = 0, tot = 0;
    int myb = (int)blockIdx.x;
    for (int b = 0; b < NB; b++) {
        int x = sb[b];
        if (b < myb) pre += x;
        tot += x;
    }
    int base = myb * 1024 + t * 4;
    int v[4];
    int tsum = 0;
#pragma unroll
    for (int j = 0; j < 4; j++) {
        int idx = base + j;
        v[j] = (idx < N_NODES) ? off[idx] : 0;
        tsum += v[j];
    }
    s[t] = tsum;
    __syncthreads();
    for (int o = 1; o < 256; o <<= 1) {
        int x = (t >= o) ? s[t - o] : 0;
        __syncthreads();
        s[t] += x;
        __syncthreads();
    }
    int excl = s[t] - tsum + pre;
#pragma unroll
    for (int j = 0; j < 4; j++) {
        int idx = base + j;
        if (idx < N_NODES) {
            off[idx] = excl;
            woff[idx] = excl;
            excl += v[j];
        }
    }
    if (myb == 0 && t == 0) off[N_NODES] = tot;
}

// scatter edges into dst-grouped order; ONE packed 16B record per edge:
// {src, bias(h0,h1) fp16x2, bias(h2,h3) fp16x2, pad}
__global__ void scatter_kernel(const int* __restrict__ src_idx,
                               const int* __restrict__ dst_idx,
                               const float* __restrict__ edge_feat,
                               const float* __restrict__ We,
                               const float* __restrict__ be,
                               int* __restrict__ woff,
                               ix4* __restrict__ prec) {
    int e = blockIdx.x * blockDim.x + threadIdx.x;
    if (e >= N_EDGES) return;
    int d = dst_idx[e];
    int s = src_idx[e];
    const fx4* ep = (const fx4*)(edge_feat + (long)e * 16);
    fx4 e0 = __builtin_nontemporal_load(ep);
    fx4 e1 = __builtin_nontemporal_load(ep + 1);
    fx4 e2 = __builtin_nontemporal_load(ep + 2);
    fx4 e3 = __builtin_nontemporal_load(ep + 3);
    int pos = atomicAdd(&woff[d], 1);
    float bp[4];
#pragma unroll
    for (int h = 0; h < NH; h++) {
        const float4* wp = (const float4*)(We + h * 16);
        float4 w0 = wp[0], w1 = wp[1], w2 = wp[2], w3 = wp[3];
        float acc = be[h];
        acc += e0.x * w0.x + e0.y * w0.y + e0.z * w0.z + e0.w * w0.w;
        acc += e1.x * w1.x + e1.y * w1.y + e1.z * w1.z + e1.w * w1.w;
        acc += e2.x * w2.x + e2.y * w2.y + e2.z * w2.z + e2.w * w2.w;
        acc += e3.x * w3.x + e3.y * w3.y + e3.z * w3.z + e3.w * w3.w;
        bp[h] = acc;
    }
    __half2 b01 = __halves2half2(__float2half_rn(bp[0]), __float2half_rn(bp[1]));
    __half2 b23 = __halves2half2(__float2half_rn(bp[2]), __float2half_rn(bp[3]));
    ix4 rec;
    rec.x = s;
    rec.y = __builtin_bit_cast(int, b01);
    rec.z = __builtin_bit_cast(int, b23);
    rec.w = 0;
    __builtin_nontemporal_store(rec, &prec[pos]);
}

// ---- projections (LDS-tiled); K/V stored fp16 ------------------------------
// bid%2 == 0: Q from dst_feat (4 waves x 32 rows)
// bid%2 == 1: K+V from src_feat (waves 0-1: K over 64 rows each; waves 2-3: V)
// src_feat is streamed from HBM ONCE (was twice).
__global__ __launch_bounds__(256) void qkv_kernel(
    const float* __restrict__ dst_feat, const float* __restrict__ src_feat,
    const float* __restrict__ Wq, const float* __restrict__ Wk,
    const float* __restrict__ Wv,
    float* __restrict__ Q, __half* __restrict__ KVh) {
    __shared__ float ftile[PT * 64];
    int bid = blockIdx.x;
    int m = bid & 1;
    int t = bid >> 1;
    int base = t * PT;
    int rows = N_NODES - base;
    if (rows > PT) rows = PT;
    int lane = threadIdx.x & 63;
    int wid = threadIdx.x >> 6;
    const float* F = m ? src_feat : dst_feat;
    int nf4 = rows * 16;
    const fx4* gf = (const fx4*)(F + (long)base * 64);
    fx4* lf = (fx4*)ftile;
    for (int i = threadIdx.x; i < nf4; i += 256)
        lf[i] = __builtin_nontemporal_load(gf + i);
    const float* W = (m == 0) ? Wq : ((wid < 2) ? Wk : Wv);
    float4 w4[16];
    const float4* wp = (const float4*)(W + lane * 64);
#pragma unroll
    for (int j = 0; j < 16; j++) w4[j] = wp[j];
    __syncthreads();
    int r0, r1;
    if (m == 0) { r0 = wid * 32; r1 = r0 + 32; }
    else        { r0 = (wid & 1) * 64; r1 = r0 + 64; }
    if (r1 > rows) r1 = rows;
    for (int r = r0; r < r1; r++) {
        const float4* fp = (const float4*)(ftile + r * 64);
        float a0 = 0.f, a1 = 0.f, a2 = 0.f, a3 = 0.f;
#pragma unroll
        for (int j = 0; j < 16; j += 4) {
            float4 f0 = fp[j], f1 = fp[j + 1], f2 = fp[j + 2], f3 = fp[j + 3];
            a0 += f0.x * w4[j].x + f0.y * w4[j].y + f0.z * w4[j].z + f0.w * w4[j].w;
            a1 += f1.x * w4[j+1].x + f1.y * w4[j+1].y + f1.z * w4[j+1].z + f1.w * w4[j+1].w;
            a2 += f2.x * w4[j+2].x + f2.y * w4[j+2].y + f2.z * w4[j+2].z + f2.w * w4[j+2].w;
            a3 += f3.x * w4[j+3].x + f3.y * w4[j+3].y + f3.z * w4[j+3].z + f3.w * w4[j+3].w;
        }
        float acc = (a0 + a1) + (a2 + a3);
        long node = base + r;
        if (m == 0)
            __builtin_nontemporal_store(acc, &Q[node * 64 + lane]);
        else if (wid < 2)
            KVh[node * 128 + lane] = __float2half_rn(acc);
        else
            KVh[node * 128 + 64 + lane] = __float2half_rn(acc);
    }
}

// ---- fused score + softmax + aggregate (no max subtraction; scores bounded) -
// Score layout: lane = edge_slot*4 + head. Agg layout: lane = head*16 + dim.
// Writes hv in-place over Q.
// Pipelined: next group's off pair and first prec record are prefetched during
// the current group's compute; V-row gathers run only over valid slots
// (chunked by 4 to keep static unrolling).
__global__ __launch_bounds__(256) void agg_kernel(
    float* QH, const __half* __restrict__ KVh,
    const int* __restrict__ off, const ix4* __restrict__ prec) {
    int lane = threadIdx.x & 63;
    int wid = threadIdx.x >> 6;
    int h = lane & 3;    // score-layout head
    int es = lane >> 2;  // score-layout edge slot
    int ha = lane >> 4;  // agg-layout head
    int g = blockIdx.x;
    int stride = gridDim.x;
    if (g >= AGG_GROUPS) return;
    int beg = off[g * 4 + wid];
    int end = off[g * 4 + wid + 1];
    ix4 rec0 = {0, 0, 0, 0};
    {
        int cnt = end - beg;
        if (cnt > 0) {
            int sl = es < cnt ? es : cnt - 1;
            rec0 = __builtin_nontemporal_load(&prec[beg + sl]);
        }
    }
    while (true) {
        int gn = g + stride;
        bool more = gn < AGG_GROUPS;
        int nbeg = 0, nend = 0;
        if (more) {  // issue next group's offsets early; latency hides under compute
            nbeg = off[gn * 4 + wid];
            nend = off[gn * 4 + wid + 1];
        }
        int node = g * 4 + wid;
        const fx4* qp = (const fx4*)(QH + (long)node * 64 + h * 16);
        fx4 q0 = __builtin_nontemporal_load(qp);
        fx4 q1 = __builtin_nontemporal_load(qp + 1);
        fx4 q2 = __builtin_nontemporal_load(qp + 2);
        fx4 q3 = __builtin_nontemporal_load(qp + 3);
        float den = 0.f, acc = 0.f;
        ix4 rec = rec0;
        for (int b = beg; b < end; b += 16) {
            int cnt = end - b;
            if (cnt > 16) cnt = 16;
            int bn = b + 16;
            ix4 recn = rec;
            if (bn < end) {  // prefetch next K-step's record
                int c2 = end - bn;
                int sl = es < c2 ? es : c2 - 1;
                recn = __builtin_nontemporal_load(&prec[bn + sl]);
            }
            int s = rec.x;
            unsigned u = (h < 2) ? (unsigned)rec.y : (unsigned)rec.z;
            unsigned hw = (h & 1) ? (u >> 16) : (u & 0xffffu);
            float bias = __half2float(__ushort_as_half((unsigned short)hw));
            // K fragment: 16 halves (32B), loaded as 2 float4 (cached: reused)
            const float4* kp4 = (const float4*)(KVh + (long)s * 128 + h * 16);
            float4 kr0 = kp4[0], kr1 = kp4[1];
            const __half2* kh0 = (const __half2*)&kr0;
            const __half2* kh1 = (const __half2*)&kr1;
            float d0 = 0.f, d1 = 0.f;
            float2 kf;
            kf = __half22float2(kh0[0]); d0 += q0.x * kf.x + q0.y * kf.y;
            kf = __half22float2(kh0[1]); d1 += q0.z * kf.x + q0.w * kf.y;
            kf = __half22float2(kh0[2]); d0 += q1.x * kf.x + q1.y * kf.y;
            kf = __half22float2(kh0[3]); d1 += q1.z * kf.x + q1.w * kf.y;
            kf = __half22float2(kh1[0]); d0 += q2.x * kf.x + q2.y * kf.y;
            kf = __half22float2(kh1[1]); d1 += q2.z * kf.x + q2.w * kf.y;
            kf = __half22float2(kh1[2]); d0 += q3.x * kf.x + q3.y * kf.y;
            kf = __half22float2(kh1[3]); d1 += q3.z * kf.x + q3.w * kf.y;
            float sc = (d0 + d1) * 0.25f + bias;
            bool valid = es < cnt;
            float p = valid ? __expf(sc) : 0.f;  // no max: scores bounded ~|10|
            den += p;                             // reduced once after the loop
            // V gathers + accumulate over VALID slots only (chunked by 4;
            // in-chunk overshoot has p==0 and a clamped, valid address)
            float a0 = 0.f, a1 = 0.f, a2 = 0.f, a3 = 0.f;
            for (int e0 = 0; e0 < cnt; e0 += 4) {
                int s0 = __shfl(s, (e0 + 0) * 4, 64);
                int s1 = __shfl(s, (e0 + 1) * 4, 64);
                int s2 = __shfl(s, (e0 + 2) * 4, 64);
                int s3 = __shfl(s, (e0 + 3) * 4, 64);
                float v0 = __half2float(KVh[(long)s0 * 128 + 64 + lane]);
                float v1 = __half2float(KVh[(long)s1 * 128 + 64 + lane]);
                float v2 = __half2float(KVh[(long)s2 * 128 + 64 + lane]);
                float v3 = __half2float(KVh[(long)s3 * 128 + 64 + lane]);
                float p0 = __shfl(p, (e0 + 0) * 4 + ha, 64);
                float p1 = __shfl(p, (e0 + 1) * 4 + ha, 64);
                float p2 = __shfl(p, (e0 + 2) * 4 + ha, 64);
                float p3 = __shfl(p, (e0 + 3) * 4 + ha, 64);
                a0 += p0 * v0;
                a1 += p1 * v1;
                a2 += p2 * v2;
                a3 += p3 * v3;
            }
            acc += (a0 + a1) + (a2 + a3);
            rec = recn;
        }
        if (more) {  // prefetch next group's first record (nbeg just landed)
            int cnt = nend - nbeg;
            if (cnt > 0) {
                int sl = es < cnt ? es : cnt - 1;
                rec0 = __builtin_nontemporal_load(&prec[nbeg + sl]);
            }
        }
        den += __shfl_xor(den, 4, 64);
        den += __shfl_xor(den, 8, 64);
        den += __shfl_xor(den, 16, 64);
        den += __shfl_xor(den, 32, 64);
        float denA = __shfl(den, ha, 64);
        float hv = (denA > 0.f) ? acc / denA : 0.f;
        __builtin_nontemporal_store(hv, &QH[(long)node * 64 + lane]);
        if (!more) break;
        g = gn;
        beg = nbeg;
        end = nend;
    }
}

// ---- output projection: out = H @ Wo.T + bo (LDS-tiled) --------------------
__global__ __launch_bounds__(256) void oproj_kernel(
    const float* __restrict__ H, const float* __restrict__ Wo,
    const float* __restrict__ bo, float* __restrict__ out) {
    __shared__ float ftile[PT * 64];
    int base = blockIdx.x * PT;
    int rows = N_NODES - base;
    if (rows > PT) rows = PT;
    int lane = threadIdx.x & 63;
    int wid = threadIdx.x >> 6;
    float4 w4[16];
    const float4* wp = (const float4*)(Wo + lane * 64);
#pragma unroll
    for (int j = 0; j < 16; j++) w4[j] = wp[j];
    float bias = bo[lane];
    int nf4 = rows * 16;
    const fx4* gf = (const fx4*)(H + (long)base * 64);
    fx4* lf = (fx4*)ftile;
    for (int i = threadIdx.x; i < nf4; i += 256)
        lf[i] = __builtin_nontemporal_load(gf + i);
    __syncthreads();
    int rend = wid * 32 + 32;
    if (rend > rows) rend = rows;
    for (int r = wid * 32; r < rend; r++) {
        const float4* fp = (const float4*)(ftile + r * 64);
        float a0 = bias, a1 = 0.f, a2 = 0.f, a3 = 0.f;
#pragma unroll
        for (int j = 0; j < 16; j += 4) {
            float4 f0 = fp[j], f1 = fp[j + 1], f2 = fp[j + 2], f3 = fp[j + 3];
            a0 += f0.x * w4[j].x + f0.y * w4[j].y + f0.z * w4[j].z + f0.w * w4[j].w;
            a1 += f1.x * w4[j+1].x + f1.y * w4[j+1].y + f1.z * w4[j+1].z + f1.w * w4[j+1].w;
            a2 += f2.x * w4[j+2].x + f2.y * w4[j+2].y + f2.z * w4[j+2].z + f2.w * w4[j+2].w;
            a3 += f3.x * w4[j+3].x + f3.y * w4[j+3].y + f3.z * w4[j+3].z + f3.w * w4[j+3].w;
        }
        __builtin_nontemporal_store((a0 + a1) + (a2 + a3),
                                    &out[(long)(base + r) * 64 + lane]);
    }
}

extern "C" void kernel_launch(void* const* d_in, const int* in_sizes, int n_in,
                              void* d_out, int out_size, void* d_ws, size_t ws_size,
                              hipStream_t stream) {
    const float* src_feat  = (const float*)d_in[0];
    const float* dst_feat  = (const float*)d_in[1];
    const float* edge_feat = (const float*)d_in[2];
    const int*   src_idx   = (const int*)d_in[3];
    const int*   dst_idx   = (const int*)d_in[4];
    const float* Wq        = (const float*)d_in[5];
    const float* Wk        = (const float*)d_in[6];
    const float* Wv        = (const float*)d_in[7];
    const float* We        = (const float*)d_in[8];
    const float* be        = (const float*)d_in[9];
    const float* Wo        = (const float*)d_in[10];
    const float* bo        = (const float*)d_in[11];
    float* out = (float*)d_out;

    // ws layout
    float*  Q    = (float*)d_ws;                          // N*64 f (also hv out)
    __half* KVh  = (__half*)(Q + (size_t)N_NODES * 64);   // N*128 h
    ix4*    prec = (ix4*)(KVh + (size_t)N_NODES * 128);   // E recs (16B)
    int*    off  = (int*)(prec + (size_t)N_EDGES);        // N+1
    int*    woff = off + (N_NODES + 1);                   // N
    int*    bsum = woff + N_NODES;                        // NB

    (void)hipMemsetAsync(off, 0, (N_NODES + 1) * sizeof(int), stream);
    hist_kernel<<<(N_EDGES / 4 + 255) / 256, 256, 0, stream>>>(dst_idx, off);
    scanA_kernel<<<NB, 256, 0, stream>>>(off, bsum);
    scanC_kernel<<<NB, 256, 0, stream>>>(off, bsum, woff);
    scatter_kernel<<<(N_EDGES + 255) / 256, 256, 0, stream>>>(
        src_idx, dst_idx, edge_feat, We, be, woff, prec);
    qkv_kernel<<<NT * 2, 256, 0, stream>>>(dst_feat, src_feat, Wq, Wk, Wv, Q, KVh);
    agg_kernel<<<2048, 256, 0, stream>>>(Q, KVh, off, prec);
    oproj_kernel<<<NT, 256, 0, stream>>>(Q, Wo, bo, out);
}

// Round 3
// 370.143 us; speedup vs baseline: 1.0889x; 1.0889x over previous
//
#include <hip/hip_runtime.h>
#include <hip/hip_fp16.h>
#include <math.h>

#define N_NODES 100000
#define N_EDGES 1600000
#define NH 4
#define HD 16
#define NB 98             // ceil(100000/1024) scan blocks
#define AGG_GROUPS 25000  // N_NODES/4
#define PT 128            // nodes per projection tile
#define NT 782            // ceil(100000/128)

typedef float fx4 __attribute__((ext_vector_type(4)));
typedef int   ix4 __attribute__((ext_vector_type(4)));

// ---- CSR build -------------------------------------------------------------

// off[] must be zeroed (hipMemsetAsync) before this
__global__ void hist_kernel(const int* __restrict__ dst_idx, int* __restrict__ off) {
    int tid = blockIdx.x * blockDim.x + threadIdx.x;
    int base = tid * 4;
    if (base + 3 < N_EDGES) {
        ix4 d = __builtin_nontemporal_load((const ix4*)dst_idx + tid);
        atomicAdd(&off[d.x], 1);
        atomicAdd(&off[d.y], 1);
        atomicAdd(&off[d.z], 1);
        atomicAdd(&off[d.w], 1);
    } else {
        for (int j = base; j < N_EDGES; j++) atomicAdd(&off[dst_idx[j]], 1);
    }
}

// per-block sums of 1024-element chunks
__global__ void scanA_kernel(const int* __restrict__ off, int* __restrict__ bsum) {
    __shared__ int s[256];
    int t = threadIdx.x;
    int base = blockIdx.x * 1024 + t * 4;
    int v = 0;
#pragma unroll
    for (int j = 0; j < 4; j++) {
        int idx = base + j;
        if (idx < N_NODES) v += off[idx];
    }
    s[t] = v;
    __syncthreads();
    for (int o = 128; o > 0; o >>= 1) {
        if (t < o) s[t] += s[t + o];
        __syncthreads();
    }
    if (t == 0) bsum[blockIdx.x] = s[0];
}

// in-place exclusive scan of counts -> offsets; copy to woff.
// Computes its own block-prefix from the raw bsum array (scanB folded in).
__global__ void scanC_kernel(int* __restrict__ off, const int* __restrict__ bsum,
                             int* __restrict__ woff) {
    __shared__ int sb[NB];
    __shared__ int s[256];
    int t = threadIdx.x;
    if (t < NB) sb[t] = bsum[t];
    __syncthreads();
    int pre = 0, tot = 0;
    int myb = (int)blockIdx.x;
    for (int b = 0; b < NB; b++) {
        int x = sb[b];
        if (b < myb) pre += x;
        tot += x;
    }
    int base = myb * 1024 + t * 4;
    int v[4];
    int tsum = 0;
#pragma unroll
    for (int j = 0; j < 4; j++) {
        int idx = base + j;
        v[j] = (idx < N_NODES) ? off[idx] : 0;
        tsum += v[j];
    }
    s[t] = tsum;
    __syncthreads();
    for (int o = 1; o < 256; o <<= 1) {
        int x = (t >= o) ? s[t - o] : 0;
        __syncthreads();
        s[t] += x;
        __syncthreads();
    }
    int excl = s[t] - tsum + pre;
#pragma unroll
    for (int j = 0; j < 4; j++) {
        int idx = base + j;
        if (idx < N_NODES) {
            off[idx] = excl;
            woff[idx] = excl;
            excl += v[j];
        }
    }
    if (myb == 0 && t == 0) off[N_NODES] = tot;
}

// scatter edges into dst-grouped order; ONE packed 16B record per edge:
// {src, bias(h0,h1) fp16x2, bias(h2,h3) fp16x2, pad}
// prec store is PLAIN (cached): random 16B NT stores defeat L2 write merging.
__global__ void scatter_kernel(const int* __restrict__ src_idx,
                               const int* __restrict__ dst_idx,
                               const float* __restrict__ edge_feat,
                               const float* __restrict__ We,
                               const float* __restrict__ be,
                               int* __restrict__ woff,
                               ix4* __restrict__ prec) {
    int e = blockIdx.x * blockDim.x + threadIdx.x;
    if (e >= N_EDGES) return;
    int d = dst_idx[e];
    int s = src_idx[e];
    const fx4* ep = (const fx4*)(edge_feat + (long)e * 16);
    fx4 e0 = __builtin_nontemporal_load(ep);
    fx4 e1 = __builtin_nontemporal_load(ep + 1);
    fx4 e2 = __builtin_nontemporal_load(ep + 2);
    fx4 e3 = __builtin_nontemporal_load(ep + 3);
    int pos = atomicAdd(&woff[d], 1);
    float bp[4];
#pragma unroll
    for (int h = 0; h < NH; h++) {
        const float4* wp = (const float4*)(We + h * 16);
        float4 w0 = wp[0], w1 = wp[1], w2 = wp[2], w3 = wp[3];
        float acc = be[h];
        acc += e0.x * w0.x + e0.y * w0.y + e0.z * w0.z + e0.w * w0.w;
        acc += e1.x * w1.x + e1.y * w1.y + e1.z * w1.z + e1.w * w1.w;
        acc += e2.x * w2.x + e2.y * w2.y + e2.z * w2.z + e2.w * w2.w;
        acc += e3.x * w3.x + e3.y * w3.y + e3.z * w3.z + e3.w * w3.w;
        bp[h] = acc;
    }
    __half2 b01 = __halves2half2(__float2half_rn(bp[0]), __float2half_rn(bp[1]));
    __half2 b23 = __halves2half2(__float2half_rn(bp[2]), __float2half_rn(bp[3]));
    ix4 rec;
    rec.x = s;
    rec.y = __builtin_bit_cast(int, b01);
    rec.z = __builtin_bit_cast(int, b23);
    rec.w = 0;
    prec[pos] = rec;
}

// ---- projections (LDS-tiled); K/V stored fp16 ------------------------------
// bid%2 == 0: Q from dst_feat (4 waves x 32 rows)
// bid%2 == 1: K+V from src_feat (waves 0-1: K over 64 rows each; waves 2-3: V)
// src_feat is streamed from HBM ONCE (was twice).
__global__ __launch_bounds__(256) void qkv_kernel(
    const float* __restrict__ dst_feat, const float* __restrict__ src_feat,
    const float* __restrict__ Wq, const float* __restrict__ Wk,
    const float* __restrict__ Wv,
    float* __restrict__ Q, __half* __restrict__ KVh) {
    __shared__ float ftile[PT * 64];
    int bid = blockIdx.x;
    int m = bid & 1;
    int t = bid >> 1;
    int base = t * PT;
    int rows = N_NODES - base;
    if (rows > PT) rows = PT;
    int lane = threadIdx.x & 63;
    int wid = threadIdx.x >> 6;
    const float* F = m ? src_feat : dst_feat;
    int nf4 = rows * 16;
    const fx4* gf = (const fx4*)(F + (long)base * 64);
    fx4* lf = (fx4*)ftile;
    for (int i = threadIdx.x; i < nf4; i += 256)
        lf[i] = __builtin_nontemporal_load(gf + i);
    const float* W = (m == 0) ? Wq : ((wid < 2) ? Wk : Wv);
    float4 w4[16];
    const float4* wp = (const float4*)(W + lane * 64);
#pragma unroll
    for (int j = 0; j < 16; j++) w4[j] = wp[j];
    __syncthreads();
    int r0, r1;
    if (m == 0) { r0 = wid * 32; r1 = r0 + 32; }
    else        { r0 = (wid & 1) * 64; r1 = r0 + 64; }
    if (r1 > rows) r1 = rows;
    for (int r = r0; r < r1; r++) {
        const float4* fp = (const float4*)(ftile + r * 64);
        float a0 = 0.f, a1 = 0.f, a2 = 0.f, a3 = 0.f;
#pragma unroll
        for (int j = 0; j < 16; j += 4) {
            float4 f0 = fp[j], f1 = fp[j + 1], f2 = fp[j + 2], f3 = fp[j + 3];
            a0 += f0.x * w4[j].x + f0.y * w4[j].y + f0.z * w4[j].z + f0.w * w4[j].w;
            a1 += f1.x * w4[j+1].x + f1.y * w4[j+1].y + f1.z * w4[j+1].z + f1.w * w4[j+1].w;
            a2 += f2.x * w4[j+2].x + f2.y * w4[j+2].y + f2.z * w4[j+2].z + f2.w * w4[j+2].w;
            a3 += f3.x * w4[j+3].x + f3.y * w4[j+3].y + f3.z * w4[j+3].z + f3.w * w4[j+3].w;
        }
        float acc = (a0 + a1) + (a2 + a3);
        long node = base + r;
        if (m == 0)
            Q[node * 64 + lane] = acc;
        else if (wid < 2)
            KVh[node * 128 + lane] = __float2half_rn(acc);
        else
            KVh[node * 128 + 64 + lane] = __float2half_rn(acc);
    }
}

// ---- fused score + softmax + aggregate (no max subtraction; scores bounded) -
// Score layout: lane = edge_slot*4 + head. Agg layout: lane = head*16 + dim.
// Writes hv in-place over Q.
// Round-0 memory pattern (static 16-wide V gather, plain cached loads) +
// software pipeline: next K-step's prec record and next group's off pair /
// first record are prefetched during current compute. Den reduced once/group.
__global__ __launch_bounds__(256) void agg_kernel(
    float* QH, const __half* __restrict__ KVh,
    const int* __restrict__ off, const ix4* __restrict__ prec) {
    int lane = threadIdx.x & 63;
    int wid = threadIdx.x >> 6;
    int h = lane & 3;    // score-layout head
    int es = lane >> 2;  // score-layout edge slot
    int ha = lane >> 4;  // agg-layout head
    int g = blockIdx.x;
    int stride = gridDim.x;
    if (g >= AGG_GROUPS) return;
    int beg = off[g * 4 + wid];
    int end = off[g * 4 + wid + 1];
    ix4 rec0 = {0, 0, 0, 0};
    if (end > beg) {
        int cnt = end - beg;
        int sl = es < cnt ? es : cnt - 1;
        rec0 = prec[beg + sl];
    }
    while (true) {
        int gn = g + stride;
        bool more = gn < AGG_GROUPS;
        int nbeg = 0, nend = 0;
        if (more) {  // issue next group's offsets early; latency hides under compute
            nbeg = off[gn * 4 + wid];
            nend = off[gn * 4 + wid + 1];
        }
        int node = g * 4 + wid;
        const float4* qp = (const float4*)(QH + (long)node * 64 + h * 16);
        float4 q0 = qp[0], q1 = qp[1], q2 = qp[2], q3 = qp[3];
        float den = 0.f, acc = 0.f;
        ix4 rec = rec0;
        for (int b = beg; b < end; b += 16) {
            int bn = b + 16;
            ix4 recn = rec;
            if (bn < end) {  // prefetch next K-step's record
                int c2 = end - bn;
                int sl = es < c2 ? es : c2 - 1;
                recn = prec[bn + sl];
            }
            int s = rec.x;
            unsigned u = (h < 2) ? (unsigned)rec.y : (unsigned)rec.z;
            unsigned hw = (h & 1) ? (u >> 16) : (u & 0xffffu);
            float bias = __half2float(__ushort_as_half((unsigned short)hw));
            // K fragment: 16 halves (32B), loaded as 2 float4
            const float4* kp4 = (const float4*)(KVh + (long)s * 128 + h * 16);
            float4 kr0 = kp4[0], kr1 = kp4[1];
            // independent V-row gathers (fp16, agg layout) — static 16-wide
            // for max memory-level parallelism (clamped slots are cache hits)
            float vv[16];
#pragma unroll
            for (int e = 0; e < 16; e++) {
                int se = __shfl(s, e * 4, 64);
                vv[e] = __half2float(KVh[(long)se * 128 + 64 + lane]);
            }
            const __half2* kh0 = (const __half2*)&kr0;
            const __half2* kh1 = (const __half2*)&kr1;
            float d0 = 0.f, d1 = 0.f;
            float2 kf;
            kf = __half22float2(kh0[0]); d0 += q0.x * kf.x + q0.y * kf.y;
            kf = __half22float2(kh0[1]); d1 += q0.z * kf.x + q0.w * kf.y;
            kf = __half22float2(kh0[2]); d0 += q1.x * kf.x + q1.y * kf.y;
            kf = __half22float2(kh0[3]); d1 += q1.z * kf.x + q1.w * kf.y;
            kf = __half22float2(kh1[0]); d0 += q2.x * kf.x + q2.y * kf.y;
            kf = __half22float2(kh1[1]); d1 += q2.z * kf.x + q2.w * kf.y;
            kf = __half22float2(kh1[2]); d0 += q3.x * kf.x + q3.y * kf.y;
            kf = __half22float2(kh1[3]); d1 += q3.z * kf.x + q3.w * kf.y;
            float sc = (d0 + d1) * 0.25f + bias;
            bool valid = (b + es) < end;
            float p = valid ? __expf(sc) : 0.f;  // no max: scores bounded ~|10|
            den += p;                             // reduced once after the loop
            float pe[16];
#pragma unroll
            for (int e = 0; e < 16; e++) pe[e] = __shfl(p, e * 4 + ha, 64);
            float a0 = 0.f, a1 = 0.f, a2 = 0.f, a3 = 0.f;
#pragma unroll
            for (int e = 0; e < 16; e += 4) {
                a0 += pe[e] * vv[e];
                a1 += pe[e + 1] * vv[e + 1];
                a2 += pe[e + 2] * vv[e + 2];
                a3 += pe[e + 3] * vv[e + 3];
            }
            acc += (a0 + a1) + (a2 + a3);
            rec = recn;
        }
        if (more && nend > nbeg) {  // prefetch next group's first record
            int cnt = nend - nbeg;
            int sl = es < cnt ? es : cnt - 1;
            rec0 = prec[nbeg + sl];
        }
        den += __shfl_xor(den, 4, 64);
        den += __shfl_xor(den, 8, 64);
        den += __shfl_xor(den, 16, 64);
        den += __shfl_xor(den, 32, 64);
        float denA = __shfl(den, ha, 64);
        float hv = (denA > 0.f) ? acc / denA : 0.f;
        QH[(long)node * 64 + lane] = hv;
        if (!more) break;
        g = gn;
        beg = nbeg;
        end = nend;
    }
}

// ---- output projection: out = H @ Wo.T + bo (LDS-tiled) --------------------
__global__ __launch_bounds__(256) void oproj_kernel(
    const float* __restrict__ H, const float* __restrict__ Wo,
    const float* __restrict__ bo, float* __restrict__ out) {
    __shared__ float ftile[PT * 64];
    int base = blockIdx.x * PT;
    int rows = N_NODES - base;
    if (rows > PT) rows = PT;
    int lane = threadIdx.x & 63;
    int wid = threadIdx.x >> 6;
    float4 w4[16];
    const float4* wp = (const float4*)(Wo + lane * 64);
#pragma unroll
    for (int j = 0; j < 16; j++) w4[j] = wp[j];
    float bias = bo[lane];
    int nf4 = rows * 16;
    const fx4* gf = (const fx4*)(H + (long)base * 64);
    fx4* lf = (fx4*)ftile;
    for (int i = threadIdx.x; i < nf4; i += 256)
        lf[i] = __builtin_nontemporal_load(gf + i);
    __syncthreads();
    int rend = wid * 32 + 32;
    if (rend > rows) rend = rows;
    for (int r = wid * 32; r < rend; r++) {
        const float4* fp = (const float4*)(ftile + r * 64);
        float a0 = bias, a1 = 0.f, a2 = 0.f, a3 = 0.f;
#pragma unroll
        for (int j = 0; j < 16; j += 4) {
            float4 f0 = fp[j], f1 = fp[j + 1], f2 = fp[j + 2], f3 = fp[j + 3];
            a0 += f0.x * w4[j].x + f0.y * w4[j].y + f0.z * w4[j].z + f0.w * w4[j].w;
            a1 += f1.x * w4[j+1].x + f1.y * w4[j+1].y + f1.z * w4[j+1].z + f1.w * w4[j+1].w;
            a2 += f2.x * w4[j+2].x + f2.y * w4[j+2].y + f2.z * w4[j+2].z + f2.w * w4[j+2].w;
            a3 += f3.x * w4[j+3].x + f3.y * w4[j+3].y + f3.z * w4[j+3].z + f3.w * w4[j+3].w;
        }
        __builtin_nontemporal_store((a0 + a1) + (a2 + a3),
                                    &out[(long)(base + r) * 64 + lane]);
    }
}

extern "C" void kernel_launch(void* const* d_in, const int* in_sizes, int n_in,
                              void* d_out, int out_size, void* d_ws, size_t ws_size,
                              hipStream_t stream) {
    const float* src_feat  = (const float*)d_in[0];
    const float* dst_feat  = (const float*)d_in[1];
    const float* edge_feat = (const float*)d_in[2];
    const int*   src_idx   = (const int*)d_in[3];
    const int*   dst_idx   = (const int*)d_in[4];
    const float* Wq        = (const float*)d_in[5];
    const float* Wk        = (const float*)d_in[6];
    const float* Wv        = (const float*)d_in[7];
    const float* We        = (const float*)d_in[8];
    const float* be        = (const float*)d_in[9];
    const float* Wo        = (const float*)d_in[10];
    const float* bo        = (const float*)d_in[11];
    float* out = (float*)d_out;

    // ws layout
    float*  Q    = (float*)d_ws;                          // N*64 f (also hv out)
    __half* KVh  = (__half*)(Q + (size_t)N_NODES * 64);   // N*128 h
    ix4*    prec = (ix4*)(KVh + (size_t)N_NODES * 128);   // E recs (16B)
    int*    off  = (int*)(prec + (size_t)N_EDGES);        // N+1
    int*    woff = off + (N_NODES + 1);                   // N
    int*    bsum = woff + N_NODES;                        // NB

    (void)hipMemsetAsync(off, 0, (N_NODES + 1) * sizeof(int), stream);
    hist_kernel<<<(N_EDGES / 4 + 255) / 256, 256, 0, stream>>>(dst_idx, off);
    scanA_kernel<<<NB, 256, 0, stream>>>(off, bsum);
    scanC_kernel<<<NB, 256, 0, stream>>>(off, bsum, woff);
    scatter_kernel<<<(N_EDGES + 255) / 256, 256, 0, stream>>>(
        src_idx, dst_idx, edge_feat, We, be, woff, prec);
    qkv_kernel<<<NT * 2, 256, 0, stream>>>(dst_feat, src_feat, Wq, Wk, Wv, Q, KVh);
    agg_kernel<<<2048, 256, 0, stream>>>(Q, KVh, off, prec);
    oproj_kernel<<<NT, 256, 0, stream>>>(Q, Wo, bo, out);
}

// Round 4
// 360.072 us; speedup vs baseline: 1.1193x; 1.0280x over previous
//
#include <hip/hip_runtime.h>
#include <hip/hip_fp16.h>
#include <math.h>

#define N_NODES 100000
#define N_EDGES 1600000
#define NH 4
#define HD 16
#define NB 98             // ceil(100000/1024) scan blocks
#define AGG_GROUPS 25000  // N_NODES/4
#define PT 128            // nodes per projection tile
#define NT 782            // ceil(100000/128)

typedef float fx4 __attribute__((ext_vector_type(4)));
typedef int   ix4 __attribute__((ext_vector_type(4)));

// ---- CSR build -------------------------------------------------------------

// off[] must be zeroed (hipMemsetAsync) before this
__global__ void hist_kernel(const int* __restrict__ dst_idx, int* __restrict__ off) {
    int tid = blockIdx.x * blockDim.x + threadIdx.x;
    int base = tid * 4;
    if (base + 3 < N_EDGES) {
        int4 d = ((const int4*)dst_idx)[tid];  // cached: dst_idx reused by scatter
        atomicAdd(&off[d.x], 1);
        atomicAdd(&off[d.y], 1);
        atomicAdd(&off[d.z], 1);
        atomicAdd(&off[d.w], 1);
    } else {
        for (int j = base; j < N_EDGES; j++) atomicAdd(&off[dst_idx[j]], 1);
    }
}

// per-block sums of 1024-element chunks
__global__ void scanA_kernel(const int* __restrict__ off, int* __restrict__ bsum) {
    __shared__ int s[256];
    int t = threadIdx.x;
    int base = blockIdx.x * 1024 + t * 4;
    int v = 0;
#pragma unroll
    for (int j = 0; j < 4; j++) {
        int idx = base + j;
        if (idx < N_NODES) v += off[idx];
    }
    s[t] = v;
    __syncthreads();
    for (int o = 128; o > 0; o >>= 1) {
        if (t < o) s[t] += s[t + o];
        __syncthreads();
    }
    if (t == 0) bsum[blockIdx.x] = s[0];
}

// in-place exclusive scan of counts -> offsets; copy to woff.
// Computes its own block-prefix from the raw bsum array (scanB folded in).
__global__ void scanC_kernel(int* __restrict__ off, const int* __restrict__ bsum,
                             int* __restrict__ woff) {
    __shared__ int sb[NB];
    __shared__ int s[256];
    int t = threadIdx.x;
    if (t < NB) sb[t] = bsum[t];
    __syncthreads();
    int pre = 0, tot = 0;
    int myb = (int)blockIdx.x;
    for (int b = 0; b < NB; b++) {
        int x = sb[b];
        if (b < myb) pre += x;
        tot += x;
    }
    int base = myb * 1024 + t * 4;
    int v[4];
    int tsum = 0;
#pragma unroll
    for (int j = 0; j < 4; j++) {
        int idx = base + j;
        v[j] = (idx < N_NODES) ? off[idx] : 0;
        tsum += v[j];
    }
    s[t] = tsum;
    __syncthreads();
    for (int o = 1; o < 256; o <<= 1) {
        int x = (t >= o) ? s[t - o] : 0;
        __syncthreads();
        s[t] += x;
        __syncthreads();
    }
    int excl = s[t] - tsum + pre;
#pragma unroll
    for (int j = 0; j < 4; j++) {
        int idx = base + j;
        if (idx < N_NODES) {
            off[idx] = excl;
            woff[idx] = excl;
            excl += v[j];
        }
    }
    if (myb == 0 && t == 0) off[N_NODES] = tot;
}

// scatter edges into dst-grouped order; ONE packed 16B record per edge:
// {src, bias(h0,h1) fp16x2, bias(h2,h3) fp16x2, pad}
__global__ void scatter_kernel(const int* __restrict__ src_idx,
                               const int* __restrict__ dst_idx,
                               const float* __restrict__ edge_feat,
                               const float* __restrict__ We,
                               const float* __restrict__ be,
                               int* __restrict__ woff,
                               ix4* __restrict__ prec) {
    int e = blockIdx.x * blockDim.x + threadIdx.x;
    if (e >= N_EDGES) return;
    int d = dst_idx[e];
    int s = src_idx[e];
    const fx4* ep = (const fx4*)(edge_feat + (long)e * 16);
    fx4 e0 = __builtin_nontemporal_load(ep);      // true streaming, 102 MB
    fx4 e1 = __builtin_nontemporal_load(ep + 1);
    fx4 e2 = __builtin_nontemporal_load(ep + 2);
    fx4 e3 = __builtin_nontemporal_load(ep + 3);
    int pos = atomicAdd(&woff[d], 1);
    float bp[4];
#pragma unroll
    for (int h = 0; h < NH; h++) {
        const float4* wp = (const float4*)(We + h * 16);
        float4 w0 = wp[0], w1 = wp[1], w2 = wp[2], w3 = wp[3];
        float acc = be[h];
        acc += e0.x * w0.x + e0.y * w0.y + e0.z * w0.z + e0.w * w0.w;
        acc += e1.x * w1.x + e1.y * w1.y + e1.z * w1.z + e1.w * w1.w;
        acc += e2.x * w2.x + e2.y * w2.y + e2.z * w2.z + e2.w * w2.w;
        acc += e3.x * w3.x + e3.y * w3.y + e3.z * w3.z + e3.w * w3.w;
        bp[h] = acc;
    }
    __half2 b01 = __halves2half2(__float2half_rn(bp[0]), __float2half_rn(bp[1]));
    __half2 b23 = __halves2half2(__float2half_rn(bp[2]), __float2half_rn(bp[3]));
    ix4 rec;
    rec.x = s;
    rec.y = __builtin_bit_cast(int, b01);
    rec.z = __builtin_bit_cast(int, b23);
    rec.w = 0;
    prec[pos] = rec;
}

// ---- projections (LDS-tiled); K/V stored fp16 ------------------------------
// bid%2 == 0: Q from dst_feat (4 waves x 32 rows)
// bid%2 == 1: K+V from src_feat (waves 0-1: K over 64 rows each; waves 2-3: V)
// src_feat is streamed from HBM ONCE (was twice). Plain cached loads: inputs
// are LLC-resident across bench iterations.
__global__ __launch_bounds__(256) void qkv_kernel(
    const float* __restrict__ dst_feat, const float* __restrict__ src_feat,
    const float* __restrict__ Wq, const float* __restrict__ Wk,
    const float* __restrict__ Wv,
    float* __restrict__ Q, __half* __restrict__ KVh) {
    __shared__ float ftile[PT * 64];
    int bid = blockIdx.x;
    int m = bid & 1;
    int t = bid >> 1;
    int base = t * PT;
    int rows = N_NODES - base;
    if (rows > PT) rows = PT;
    int lane = threadIdx.x & 63;
    int wid = threadIdx.x >> 6;
    const float* F = m ? src_feat : dst_feat;
    int nf4 = rows * 16;
    const float4* gf = (const float4*)(F + (long)base * 64);
    float4* lf = (float4*)ftile;
    for (int i = threadIdx.x; i < nf4; i += 256) lf[i] = gf[i];
    const float* W = (m == 0) ? Wq : ((wid < 2) ? Wk : Wv);
    float4 w4[16];
    const float4* wp = (const float4*)(W + lane * 64);
#pragma unroll
    for (int j = 0; j < 16; j++) w4[j] = wp[j];
    __syncthreads();
    int r0, r1;
    if (m == 0) { r0 = wid * 32; r1 = r0 + 32; }
    else        { r0 = (wid & 1) * 64; r1 = r0 + 64; }
    if (r1 > rows) r1 = rows;
    for (int r = r0; r < r1; r++) {
        const float4* fp = (const float4*)(ftile + r * 64);
        float a0 = 0.f, a1 = 0.f, a2 = 0.f, a3 = 0.f;
#pragma unroll
        for (int j = 0; j < 16; j += 4) {
            float4 f0 = fp[j], f1 = fp[j + 1], f2 = fp[j + 2], f3 = fp[j + 3];
            a0 += f0.x * w4[j].x + f0.y * w4[j].y + f0.z * w4[j].z + f0.w * w4[j].w;
            a1 += f1.x * w4[j+1].x + f1.y * w4[j+1].y + f1.z * w4[j+1].z + f1.w * w4[j+1].w;
            a2 += f2.x * w4[j+2].x + f2.y * w4[j+2].y + f2.z * w4[j+2].z + f2.w * w4[j+2].w;
            a3 += f3.x * w4[j+3].x + f3.y * w4[j+3].y + f3.z * w4[j+3].z + f3.w * w4[j+3].w;
        }
        float acc = (a0 + a1) + (a2 + a3);
        long node = base + r;
        if (m == 0)
            Q[node * 64 + lane] = acc;
        else if (wid < 2)
            KVh[node * 128 + lane] = __float2half_rn(acc);
        else
            KVh[node * 128 + 64 + lane] = __float2half_rn(acc);
    }
}

// ---- fused score + softmax + aggregate (no max subtraction; scores bounded) -
// Score layout: lane = edge_slot*4 + head. Agg layout: lane = head*16 + dim.
// Writes hv in-place over Q.
// Static 16-wide V gather with SGPR (readlane) src broadcast: the per-slot src
// is wave-uniform, so readlane with constant lane index replaces 16
// ds_bpermute + per-lane 64-bit addressing with scalar-base loads.
// Pipeline: next K-step's prec record and next group's off pair / first record
// prefetched during current compute. Den reduced once per group.
__global__ __launch_bounds__(256) void agg_kernel(
    float* QH, const __half* __restrict__ KVh,
    const int* __restrict__ off, const ix4* __restrict__ prec) {
    int lane = threadIdx.x & 63;
    int wid = threadIdx.x >> 6;
    int h = lane & 3;    // score-layout head
    int es = lane >> 2;  // score-layout edge slot
    int ha = lane >> 4;  // agg-layout head
    int g = blockIdx.x;
    int stride = gridDim.x;
    if (g >= AGG_GROUPS) return;
    int beg = off[g * 4 + wid];
    int end = off[g * 4 + wid + 1];
    ix4 rec0 = {0, 0, 0, 0};
    if (end > beg) {
        int cnt = end - beg;
        int sl = es < cnt ? es : cnt - 1;
        rec0 = prec[beg + sl];
    }
    while (true) {
        int gn = g + stride;
        bool more = gn < AGG_GROUPS;
        int nbeg = 0, nend = 0;
        if (more) {  // issue next group's offsets early; latency hides under compute
            nbeg = off[gn * 4 + wid];
            nend = off[gn * 4 + wid + 1];
        }
        int node = g * 4 + wid;
        const float4* qp = (const float4*)(QH + (long)node * 64 + h * 16);
        float4 q0 = qp[0], q1 = qp[1], q2 = qp[2], q3 = qp[3];
        float den = 0.f, acc = 0.f;
        ix4 rec = rec0;
        for (int b = beg; b < end; b += 16) {
            int bn = b + 16;
            ix4 recn = rec;
            if (bn < end) {  // prefetch next K-step's record
                int c2 = end - bn;
                int sl = es < c2 ? es : c2 - 1;
                recn = prec[bn + sl];
            }
            int s = rec.x;
            unsigned u = (h < 2) ? (unsigned)rec.y : (unsigned)rec.z;
            unsigned hw = (h & 1) ? (u >> 16) : (u & 0xffffu);
            float bias = __half2float(__ushort_as_half((unsigned short)hw));
            // K fragment: 16 halves (32B), loaded as 2 float4
            const float4* kp4 = (const float4*)(KVh + (long)s * 128 + h * 16);
            float4 kr0 = kp4[0], kr1 = kp4[1];
            // independent V-row gathers: src broadcast via readlane -> SGPR
            // base, so each load is scalar-base + lane*2 (no LDS pipe, no
            // per-lane 64-bit addr math). Clamped slots are cache hits.
            float vv[16];
#pragma unroll
            for (int e = 0; e < 16; e++) {
                int se = __builtin_amdgcn_readlane(s, e * 4);
                vv[e] = __half2float(KVh[(long)se * 128 + 64 + lane]);
            }
            const __half2* kh0 = (const __half2*)&kr0;
            const __half2* kh1 = (const __half2*)&kr1;
            float d0 = 0.f, d1 = 0.f;
            float2 kf;
            kf = __half22float2(kh0[0]); d0 += q0.x * kf.x + q0.y * kf.y;
            kf = __half22float2(kh0[1]); d1 += q0.z * kf.x + q0.w * kf.y;
            kf = __half22float2(kh0[2]); d0 += q1.x * kf.x + q1.y * kf.y;
            kf = __half22float2(kh0[3]); d1 += q1.z * kf.x + q1.w * kf.y;
            kf = __half22float2(kh1[0]); d0 += q2.x * kf.x + q2.y * kf.y;
            kf = __half22float2(kh1[1]); d1 += q2.z * kf.x + q2.w * kf.y;
            kf = __half22float2(kh1[2]); d0 += q3.x * kf.x + q3.y * kf.y;
            kf = __half22float2(kh1[3]); d1 += q3.z * kf.x + q3.w * kf.y;
            float sc = (d0 + d1) * 0.25f + bias;
            bool valid = (b + es) < end;
            float p = valid ? __expf(sc) : 0.f;  // no max: scores bounded ~|10|
            den += p;                             // reduced once after the loop
            float pe[16];
#pragma unroll
            for (int e = 0; e < 16; e++) pe[e] = __shfl(p, e * 4 + ha, 64);
            float a0 = 0.f, a1 = 0.f, a2 = 0.f, a3 = 0.f;
#pragma unroll
            for (int e = 0; e < 16; e += 4) {
                a0 += pe[e] * vv[e];
                a1 += pe[e + 1] * vv[e + 1];
                a2 += pe[e + 2] * vv[e + 2];
                a3 += pe[e + 3] * vv[e + 3];
            }
            acc += (a0 + a1) + (a2 + a3);
            rec = recn;
        }
        if (more && nend > nbeg) {  // prefetch next group's first record
            int cnt = nend - nbeg;
            int sl = es < cnt ? es : cnt - 1;
            rec0 = prec[nbeg + sl];
        }
        den += __shfl_xor(den, 4, 64);
        den += __shfl_xor(den, 8, 64);
        den += __shfl_xor(den, 16, 64);
        den += __shfl_xor(den, 32, 64);
        float denA = __shfl(den, ha, 64);
        float hv = (denA > 0.f) ? acc / denA : 0.f;
        QH[(long)node * 64 + lane] = hv;
        if (!more) break;
        g = gn;
        beg = nbeg;
        end = nend;
    }
}

// ---- output projection: out = H @ Wo.T + bo (LDS-tiled) --------------------
__global__ __launch_bounds__(256) void oproj_kernel(
    const float* __restrict__ H, const float* __restrict__ Wo,
    const float* __restrict__ bo, float* __restrict__ out) {
    __shared__ float ftile[PT * 64];
    int base = blockIdx.x * PT;
    int rows = N_NODES - base;
    if (rows > PT) rows = PT;
    int lane = threadIdx.x & 63;
    int wid = threadIdx.x >> 6;
    float4 w4[16];
    const float4* wp = (const float4*)(Wo + lane * 64);
#pragma unroll
    for (int j = 0; j < 16; j++) w4[j] = wp[j];
    float bias = bo[lane];
    int nf4 = rows * 16;
    const float4* gf = (const float4*)(H + (long)base * 64);
    float4* lf = (float4*)ftile;
    for (int i = threadIdx.x; i < nf4; i += 256) lf[i] = gf[i];  // H is cache-hot
    __syncthreads();
    int rend = wid * 32 + 32;
    if (rend > rows) rend = rows;
    for (int r = wid * 32; r < rend; r++) {
        const float4* fp = (const float4*)(ftile + r * 64);
        float a0 = bias, a1 = 0.f, a2 = 0.f, a3 = 0.f;
#pragma unroll
        for (int j = 0; j < 16; j += 4) {
            float4 f0 = fp[j], f1 = fp[j + 1], f2 = fp[j + 2], f3 = fp[j + 3];
            a0 += f0.x * w4[j].x + f0.y * w4[j].y + f0.z * w4[j].z + f0.w * w4[j].w;
            a1 += f1.x * w4[j+1].x + f1.y * w4[j+1].y + f1.z * w4[j+1].z + f1.w * w4[j+1].w;
            a2 += f2.x * w4[j+2].x + f2.y * w4[j+2].y + f2.z * w4[j+2].z + f2.w * w4[j+2].w;
            a3 += f3.x * w4[j+3].x + f3.y * w4[j+3].y + f3.z * w4[j+3].z + f3.w * w4[j+3].w;
        }
        out[(long)(base + r) * 64 + lane] = (a0 + a1) + (a2 + a3);
    }
}

extern "C" void kernel_launch(void* const* d_in, const int* in_sizes, int n_in,
                              void* d_out, int out_size, void* d_ws, size_t ws_size,
                              hipStream_t stream) {
    const float* src_feat  = (const float*)d_in[0];
    const float* dst_feat  = (const float*)d_in[1];
    const float* edge_feat = (const float*)d_in[2];
    const int*   src_idx   = (const int*)d_in[3];
    const int*   dst_idx   = (const int*)d_in[4];
    const float* Wq        = (const float*)d_in[5];
    const float* Wk        = (const float*)d_in[6];
    const float* Wv        = (const float*)d_in[7];
    const float* We        = (const float*)d_in[8];
    const float* be        = (const float*)d_in[9];
    const float* Wo        = (const float*)d_in[10];
    const float* bo        = (const float*)d_in[11];
    float* out = (float*)d_out;

    // ws layout
    float*  Q    = (float*)d_ws;                          // N*64 f (also hv out)
    __half* KVh  = (__half*)(Q + (size_t)N_NODES * 64);   // N*128 h
    ix4*    prec = (ix4*)(KVh + (size_t)N_NODES * 128);   // E recs (16B)
    int*    off  = (int*)(prec + (size_t)N_EDGES);        // N+1
    int*    woff = off + (N_NODES + 1);                   // N
    int*    bsum = woff + N_NODES;                        // NB

    (void)hipMemsetAsync(off, 0, (N_NODES + 1) * sizeof(int), stream);
    hist_kernel<<<(N_EDGES / 4 + 255) / 256, 256, 0, stream>>>(dst_idx, off);
    scanA_kernel<<<NB, 256, 0, stream>>>(off, bsum);
    scanC_kernel<<<NB, 256, 0, stream>>>(off, bsum, woff);
    scatter_kernel<<<(N_EDGES + 255) / 256, 256, 0, stream>>>(
        src_idx, dst_idx, edge_feat, We, be, woff, prec);
    qkv_kernel<<<NT * 2, 256, 0, stream>>>(dst_feat, src_feat, Wq, Wk, Wv, Q, KVh);
    agg_kernel<<<2048, 256, 0, stream>>>(Q, KVh, off, prec);
    oproj_kernel<<<NT, 256, 0, stream>>>(Q, Wo, bo, out);
}

// Round 5
// 332.751 us; speedup vs baseline: 1.2112x; 1.0821x over previous
//
#include <hip/hip_runtime.h>
#include <hip/hip_fp16.h>
#include <math.h>

#define N_NODES 100000
#define N_EDGES 1600000
#define NH 4
#define HD 16
#define NB 98             // ceil(100000/1024) scan blocks
#define AGG_GROUPS 25000  // N_NODES/4
#define PT 128            // nodes per projection tile (oproj)
#define NT 782            // ceil(100000/128)
#define QKV_TILES 6250    // 100000/16 node-tiles per projection
#define QKV_WAVES (3 * QKV_TILES)

typedef float fx4 __attribute__((ext_vector_type(4)));
typedef int   ix4 __attribute__((ext_vector_type(4)));
typedef _Float16 h8v __attribute__((ext_vector_type(8)));

// ---- CSR build -------------------------------------------------------------

// off[] must be zeroed (hipMemsetAsync) before this
__global__ void hist_kernel(const int* __restrict__ dst_idx, int* __restrict__ off) {
    int tid = blockIdx.x * blockDim.x + threadIdx.x;
    int base = tid * 4;
    if (base + 3 < N_EDGES) {
        int4 d = ((const int4*)dst_idx)[tid];  // cached: dst_idx reused by scatter
        atomicAdd(&off[d.x], 1);
        atomicAdd(&off[d.y], 1);
        atomicAdd(&off[d.z], 1);
        atomicAdd(&off[d.w], 1);
    } else {
        for (int j = base; j < N_EDGES; j++) atomicAdd(&off[dst_idx[j]], 1);
    }
}

// per-block sums of 1024-element chunks
__global__ void scanA_kernel(const int* __restrict__ off, int* __restrict__ bsum) {
    __shared__ int s[256];
    int t = threadIdx.x;
    int base = blockIdx.x * 1024 + t * 4;
    int v = 0;
#pragma unroll
    for (int j = 0; j < 4; j++) {
        int idx = base + j;
        if (idx < N_NODES) v += off[idx];
    }
    s[t] = v;
    __syncthreads();
    for (int o = 128; o > 0; o >>= 1) {
        if (t < o) s[t] += s[t + o];
        __syncthreads();
    }
    if (t == 0) bsum[blockIdx.x] = s[0];
}

// in-place exclusive scan of counts -> offsets; copy to woff.
// Computes its own block-prefix from the raw bsum array (scanB folded in).
__global__ void scanC_kernel(int* __restrict__ off, const int* __restrict__ bsum,
                             int* __restrict__ woff) {
    __shared__ int sb[NB];
    __shared__ int s[256];
    int t = threadIdx.x;
    if (t < NB) sb[t] = bsum[t];
    __syncthreads();
    int pre = 0, tot = 0;
    int myb = (int)blockIdx.x;
    for (int b = 0; b < NB; b++) {
        int x = sb[b];
        if (b < myb) pre += x;
        tot += x;
    }
    int base = myb * 1024 + t * 4;
    int v[4];
    int tsum = 0;
#pragma unroll
    for (int j = 0; j < 4; j++) {
        int idx = base + j;
        v[j] = (idx < N_NODES) ? off[idx] : 0;
        tsum += v[j];
    }
    s[t] = tsum;
    __syncthreads();
    for (int o = 1; o < 256; o <<= 1) {
        int x = (t >= o) ? s[t - o] : 0;
        __syncthreads();
        s[t] += x;
        __syncthreads();
    }
    int excl = s[t] - tsum + pre;
#pragma unroll
    for (int j = 0; j < 4; j++) {
        int idx = base + j;
        if (idx < N_NODES) {
            off[idx] = excl;
            woff[idx] = excl;
            excl += v[j];
        }
    }
    if (myb == 0 && t == 0) off[N_NODES] = tot;
}

// scatter edges into dst-grouped order; ONE packed 16B record per edge:
// {src, bias(h0,h1) fp16x2, bias(h2,h3) fp16x2, pad}
__global__ void scatter_kernel(const int* __restrict__ src_idx,
                               const int* __restrict__ dst_idx,
                               const float* __restrict__ edge_feat,
                               const float* __restrict__ We,
                               const float* __restrict__ be,
                               int* __restrict__ woff,
                               ix4* __restrict__ prec) {
    int e = blockIdx.x * blockDim.x + threadIdx.x;
    if (e >= N_EDGES) return;
    int d = dst_idx[e];
    int s = src_idx[e];
    const fx4* ep = (const fx4*)(edge_feat + (long)e * 16);
    fx4 e0 = __builtin_nontemporal_load(ep);      // true streaming, 102 MB
    fx4 e1 = __builtin_nontemporal_load(ep + 1);
    fx4 e2 = __builtin_nontemporal_load(ep + 2);
    fx4 e3 = __builtin_nontemporal_load(ep + 3);
    int pos = atomicAdd(&woff[d], 1);
    float bp[4];
#pragma unroll
    for (int h = 0; h < NH; h++) {
        const float4* wp = (const float4*)(We + h * 16);
        float4 w0 = wp[0], w1 = wp[1], w2 = wp[2], w3 = wp[3];
        float acc = be[h];
        acc += e0[0] * w0.x + e0[1] * w0.y + e0[2] * w0.z + e0[3] * w0.w;
        acc += e1[0] * w1.x + e1[1] * w1.y + e1[2] * w1.z + e1[3] * w1.w;
        acc += e2[0] * w2.x + e2[1] * w2.y + e2[2] * w2.z + e2[3] * w2.w;
        acc += e3[0] * w3.x + e3[1] * w3.y + e3[2] * w3.z + e3[3] * w3.w;
        bp[h] = acc;
    }
    __half2 b01 = __halves2half2(__float2half_rn(bp[0]), __float2half_rn(bp[1]));
    __half2 b23 = __halves2half2(__float2half_rn(bp[2]), __float2half_rn(bp[3]));
    ix4 rec;
    rec.x = s;
    rec.y = __builtin_bit_cast(int, b01);
    rec.z = __builtin_bit_cast(int, b23);
    rec.w = 0;
    prec[pos] = rec;
}

// ---- QKV projections via MFMA (fp16 hi/lo split = fp32-accurate) -----------
// One wave per (projection, 16-node tile). A-frag: row=lane&15, k=(lane>>4)*8+j
// (contiguous from row-major feat). B-frag: col=lane&15, same k (contiguous
// from row-major W since we need W[col][k]). D: col=lane&15, row=(lane>>4)*4+r.
// Split precision: x = hi + lo (both fp16); D = Ah*Bh + Al*Bh + Ah*Bl with
// fp32 accumulation -> residual error ~1e-6 rel (AlBl term ~2.5e-7).
__device__ __forceinline__ void pack2(fx4 a, fx4 b, h8v& hi, h8v& lo) {
#pragma unroll
    for (int j = 0; j < 4; j++) {
        float xa = a[j], xb = b[j];
        _Float16 ha = (_Float16)xa, hb = (_Float16)xb;
        hi[j] = ha;
        hi[j + 4] = hb;
        lo[j] = (_Float16)(xa - (float)ha);
        lo[j + 4] = (_Float16)(xb - (float)hb);
    }
}

__global__ __launch_bounds__(256) void qkv_kernel(
    const float* __restrict__ dst_feat, const float* __restrict__ src_feat,
    const float* __restrict__ Wq, const float* __restrict__ Wk,
    const float* __restrict__ Wv,
    float* __restrict__ Q, __half* __restrict__ KVh) {
    int lane = threadIdx.x & 63;
    int wid = threadIdx.x >> 6;
    int wave = blockIdx.x * 4 + wid;
    if (wave >= QKV_WAVES) return;
    int proj = wave / QKV_TILES;           // 0:Q 1:K 2:V
    int tile = wave - proj * QKV_TILES;
    int base = tile * 16;
    const float* F = (proj == 0) ? dst_feat : src_feat;
    const float* W = (proj == 0) ? Wq : (proj == 1) ? Wk : Wv;
    int r16 = lane & 15;
    int kg = lane >> 4;
    // A fragments: 16 floats per lane covering k = kg*8..+8 of both 32-chunks
    const fx4* fr = (const fx4*)(F + (long)(base + r16) * 64 + kg * 8);
    fx4 fa = fr[0], fb = fr[1], fc = fr[8], fd = fr[9];
    h8v Ah0, Al0, Ah1, Al1;
    pack2(fa, fb, Ah0, Al0);
    pack2(fc, fd, Ah1, Al1);
#pragma unroll
    for (int c = 0; c < 4; c++) {  // 4 col-tiles of 16
        const fx4* wr = (const fx4*)(W + (long)(c * 16 + r16) * 64 + kg * 8);
        fx4 wa = wr[0], wb = wr[1], wc = wr[8], wd = wr[9];
        h8v Bh0, Bl0, Bh1, Bl1;
        pack2(wa, wb, Bh0, Bl0);
        pack2(wc, wd, Bh1, Bl1);
        fx4 acc = {0.f, 0.f, 0.f, 0.f};
        acc = __builtin_amdgcn_mfma_f32_16x16x32_f16(Ah0, Bh0, acc, 0, 0, 0);
        acc = __builtin_amdgcn_mfma_f32_16x16x32_f16(Al0, Bh0, acc, 0, 0, 0);
        acc = __builtin_amdgcn_mfma_f32_16x16x32_f16(Ah0, Bl0, acc, 0, 0, 0);
        acc = __builtin_amdgcn_mfma_f32_16x16x32_f16(Ah1, Bh1, acc, 0, 0, 0);
        acc = __builtin_amdgcn_mfma_f32_16x16x32_f16(Al1, Bh1, acc, 0, 0, 0);
        acc = __builtin_amdgcn_mfma_f32_16x16x32_f16(Ah1, Bl1, acc, 0, 0, 0);
        int ocol = c * 16 + r16;
        long orow = base + kg * 4;
        if (proj == 0) {
#pragma unroll
            for (int r = 0; r < 4; r++)
                Q[(orow + r) * 64 + ocol] = acc[r];
        } else {
            long o64 = (proj == 1) ? 0 : 64;
#pragma unroll
            for (int r = 0; r < 4; r++)
                KVh[(orow + r) * 128 + o64 + ocol] = __float2half_rn(acc[r]);
        }
    }
}

// ---- fused score + softmax + aggregate (no max subtraction; scores bounded) -
// Score layout: lane = edge_slot*4 + head. Agg layout: lane = head*16 + dim.
// Writes hv in-place over Q.
// Static 16-wide V gather with SGPR (readlane) src broadcast; pipeline:
// next K-step's prec record and next group's off pair / first record
// prefetched during current compute. Den reduced once per group.
__global__ __launch_bounds__(256) void agg_kernel(
    float* QH, const __half* __restrict__ KVh,
    const int* __restrict__ off, const ix4* __restrict__ prec) {
    int lane = threadIdx.x & 63;
    int wid = threadIdx.x >> 6;
    int h = lane & 3;    // score-layout head
    int es = lane >> 2;  // score-layout edge slot
    int ha = lane >> 4;  // agg-layout head
    int g = blockIdx.x;
    int stride = gridDim.x;
    if (g >= AGG_GROUPS) return;
    int beg = off[g * 4 + wid];
    int end = off[g * 4 + wid + 1];
    ix4 rec0 = {0, 0, 0, 0};
    if (end > beg) {
        int cnt = end - beg;
        int sl = es < cnt ? es : cnt - 1;
        rec0 = prec[beg + sl];
    }
    while (true) {
        int gn = g + stride;
        bool more = gn < AGG_GROUPS;
        int nbeg = 0, nend = 0;
        if (more) {  // issue next group's offsets early; latency hides under compute
            nbeg = off[gn * 4 + wid];
            nend = off[gn * 4 + wid + 1];
        }
        int node = g * 4 + wid;
        const float4* qp = (const float4*)(QH + (long)node * 64 + h * 16);
        float4 q0 = qp[0], q1 = qp[1], q2 = qp[2], q3 = qp[3];
        float den = 0.f, acc = 0.f;
        ix4 rec = rec0;
        for (int b = beg; b < end; b += 16) {
            int bn = b + 16;
            ix4 recn = rec;
            if (bn < end) {  // prefetch next K-step's record
                int c2 = end - bn;
                int sl = es < c2 ? es : c2 - 1;
                recn = prec[bn + sl];
            }
            int s = rec.x;
            unsigned u = (h < 2) ? (unsigned)rec.y : (unsigned)rec.z;
            unsigned hw = (h & 1) ? (u >> 16) : (u & 0xffffu);
            float bias = __half2float(__ushort_as_half((unsigned short)hw));
            // K fragment: 16 halves (32B), loaded as 2 float4
            const float4* kp4 = (const float4*)(KVh + (long)s * 128 + h * 16);
            float4 kr0 = kp4[0], kr1 = kp4[1];
            // independent V-row gathers: src broadcast via readlane -> SGPR
            // base, so each load is scalar-base + lane*2. Clamped slots are
            // cache hits.
            float vv[16];
#pragma unroll
            for (int e = 0; e < 16; e++) {
                int se = __builtin_amdgcn_readlane(s, e * 4);
                vv[e] = __half2float(KVh[(long)se * 128 + 64 + lane]);
            }
            const __half2* kh0 = (const __half2*)&kr0;
            const __half2* kh1 = (const __half2*)&kr1;
            float d0 = 0.f, d1 = 0.f;
            float2 kf;
            kf = __half22float2(kh0[0]); d0 += q0.x * kf.x + q0.y * kf.y;
            kf = __half22float2(kh0[1]); d1 += q0.z * kf.x + q0.w * kf.y;
            kf = __half22float2(kh0[2]); d0 += q1.x * kf.x + q1.y * kf.y;
            kf = __half22float2(kh0[3]); d1 += q1.z * kf.x + q1.w * kf.y;
            kf = __half22float2(kh1[0]); d0 += q2.x * kf.x + q2.y * kf.y;
            kf = __half22float2(kh1[1]); d1 += q2.z * kf.x + q2.w * kf.y;
            kf = __half22float2(kh1[2]); d0 += q3.x * kf.x + q3.y * kf.y;
            kf = __half22float2(kh1[3]); d1 += q3.z * kf.x + q3.w * kf.y;
            float sc = (d0 + d1) * 0.25f + bias;
            bool valid = (b + es) < end;
            float p = valid ? __expf(sc) : 0.f;  // no max: scores bounded ~|10|
            den += p;                             // reduced once after the loop
            float pe[16];
#pragma unroll
            for (int e = 0; e < 16; e++) pe[e] = __shfl(p, e * 4 + ha, 64);
            float a0 = 0.f, a1 = 0.f, a2 = 0.f, a3 = 0.f;
#pragma unroll
            for (int e = 0; e < 16; e += 4) {
                a0 += pe[e] * vv[e];
                a1 += pe[e + 1] * vv[e + 1];
                a2 += pe[e + 2] * vv[e + 2];
                a3 += pe[e + 3] * vv[e + 3];
            }
            acc += (a0 + a1) + (a2 + a3);
            rec = recn;
        }
        if (more && nend > nbeg) {  // prefetch next group's first record
            int cnt = nend - nbeg;
            int sl = es < cnt ? es : cnt - 1;
            rec0 = prec[nbeg + sl];
        }
        den += __shfl_xor(den, 4, 64);
        den += __shfl_xor(den, 8, 64);
        den += __shfl_xor(den, 16, 64);
        den += __shfl_xor(den, 32, 64);
        float denA = __shfl(den, ha, 64);
        float hv = (denA > 0.f) ? acc / denA : 0.f;
        QH[(long)node * 64 + lane] = hv;
        if (!more) break;
        g = gn;
        beg = nbeg;
        end = nend;
    }
}

// ---- output projection: out = H @ Wo.T + bo (LDS-tiled) --------------------
__global__ __launch_bounds__(256) void oproj_kernel(
    const float* __restrict__ H, const float* __restrict__ Wo,
    const float* __restrict__ bo, float* __restrict__ out) {
    __shared__ float ftile[PT * 64];
    int base = blockIdx.x * PT;
    int rows = N_NODES - base;
    if (rows > PT) rows = PT;
    int lane = threadIdx.x & 63;
    int wid = threadIdx.x >> 6;
    float4 w4[16];
    const float4* wp = (const float4*)(Wo + lane * 64);
#pragma unroll
    for (int j = 0; j < 16; j++) w4[j] = wp[j];
    float bias = bo[lane];
    int nf4 = rows * 16;
    const float4* gf = (const float4*)(H + (long)base * 64);
    float4* lf = (float4*)ftile;
    for (int i = threadIdx.x; i < nf4; i += 256) lf[i] = gf[i];  // H is cache-hot
    __syncthreads();
    int rend = wid * 32 + 32;
    if (rend > rows) rend = rows;
    for (int r = wid * 32; r < rend; r++) {
        const float4* fp = (const float4*)(ftile + r * 64);
        float a0 = bias, a1 = 0.f, a2 = 0.f, a3 = 0.f;
#pragma unroll
        for (int j = 0; j < 16; j += 4) {
            float4 f0 = fp[j], f1 = fp[j + 1], f2 = fp[j + 2], f3 = fp[j + 3];
            a0 += f0.x * w4[j].x + f0.y * w4[j].y + f0.z * w4[j].z + f0.w * w4[j].w;
            a1 += f1.x * w4[j+1].x + f1.y * w4[j+1].y + f1.z * w4[j+1].z + f1.w * w4[j+1].w;
            a2 += f2.x * w4[j+2].x + f2.y * w4[j+2].y + f2.z * w4[j+2].z + f2.w * w4[j+2].w;
            a3 += f3.x * w4[j+3].x + f3.y * w4[j+3].y + f3.z * w4[j+3].z + f3.w * w4[j+3].w;
        }
        out[(long)(base + r) * 64 + lane] = (a0 + a1) + (a2 + a3);
    }
}

extern "C" void kernel_launch(void* const* d_in, const int* in_sizes, int n_in,
                              void* d_out, int out_size, void* d_ws, size_t ws_size,
                              hipStream_t stream) {
    const float* src_feat  = (const float*)d_in[0];
    const float* dst_feat  = (const float*)d_in[1];
    const float* edge_feat = (const float*)d_in[2];
    const int*   src_idx   = (const int*)d_in[3];
    const int*   dst_idx   = (const int*)d_in[4];
    const float* Wq        = (const float*)d_in[5];
    const float* Wk        = (const float*)d_in[6];
    const float* Wv        = (const float*)d_in[7];
    const float* We        = (const float*)d_in[8];
    const float* be        = (const float*)d_in[9];
    const float* Wo        = (const float*)d_in[10];
    const float* bo        = (const float*)d_in[11];
    float* out = (float*)d_out;

    // ws layout
    float*  Q    = (float*)d_ws;                          // N*64 f (also hv out)
    __half* KVh  = (__half*)(Q + (size_t)N_NODES * 64);   // N*128 h
    ix4*    prec = (ix4*)(KVh + (size_t)N_NODES * 128);   // E recs (16B)
    int*    off  = (int*)(prec + (size_t)N_EDGES);        // N+1
    int*    woff = off + (N_NODES + 1);                   // N
    int*    bsum = woff + N_NODES;                        // NB

    (void)hipMemsetAsync(off, 0, (N_NODES + 1) * sizeof(int), stream);
    hist_kernel<<<(N_EDGES / 4 + 255) / 256, 256, 0, stream>>>(dst_idx, off);
    scanA_kernel<<<NB, 256, 0, stream>>>(off, bsum);
    scanC_kernel<<<NB, 256, 0, stream>>>(off, bsum, woff);
    scatter_kernel<<<(N_EDGES + 255) / 256, 256, 0, stream>>>(
        src_idx, dst_idx, edge_feat, We, be, woff, prec);
    qkv_kernel<<<(QKV_WAVES + 3) / 4, 256, 0, stream>>>(
        dst_feat, src_feat, Wq, Wk, Wv, Q, KVh);
    agg_kernel<<<2048, 256, 0, stream>>>(Q, KVh, off, prec);
    oproj_kernel<<<NT, 256, 0, stream>>>(Q, Wo, bo, out);
}

// Round 6
// 289.111 us; speedup vs baseline: 1.3941x; 1.1509x over previous
//
#include <hip/hip_runtime.h>
#include <hip/hip_fp16.h>
#include <math.h>

#define N_NODES 100000
#define N_EDGES 1600000
#define NH 4
#define HD 16
#define NB 98             // ceil(100000/1024) scan blocks
#define AGG_GROUPS 25000  // N_NODES/4
#define QKV_TILES 6250    // 100000/16 node-tiles
#define QKV_TPG 4         // tiles per wave
#define QKV_GROUPS 1563   // ceil(6250/4)
#define QKV_WAVES (2 * QKV_GROUPS)  // Q-groups + fused-KV-groups
#define OP_GROUPS 1563    // oproj wave-groups (4 tiles each)

typedef float fx4 __attribute__((ext_vector_type(4)));
typedef int   ix4 __attribute__((ext_vector_type(4)));
typedef _Float16 h8v __attribute__((ext_vector_type(8)));

// ---- CSR build -------------------------------------------------------------

// off[] must be zeroed (hipMemsetAsync) before this
__global__ void hist_kernel(const int* __restrict__ dst_idx, int* __restrict__ off) {
    int tid = blockIdx.x * blockDim.x + threadIdx.x;
    int base = tid * 4;
    if (base + 3 < N_EDGES) {
        int4 d = ((const int4*)dst_idx)[tid];  // cached: dst_idx reused by scatter
        atomicAdd(&off[d.x], 1);
        atomicAdd(&off[d.y], 1);
        atomicAdd(&off[d.z], 1);
        atomicAdd(&off[d.w], 1);
    } else {
        for (int j = base; j < N_EDGES; j++) atomicAdd(&off[dst_idx[j]], 1);
    }
}

// per-block sums of 1024-element chunks
__global__ void scanA_kernel(const int* __restrict__ off, int* __restrict__ bsum) {
    __shared__ int s[256];
    int t = threadIdx.x;
    int base = blockIdx.x * 1024 + t * 4;
    int v = 0;
#pragma unroll
    for (int j = 0; j < 4; j++) {
        int idx = base + j;
        if (idx < N_NODES) v += off[idx];
    }
    s[t] = v;
    __syncthreads();
    for (int o = 128; o > 0; o >>= 1) {
        if (t < o) s[t] += s[t + o];
        __syncthreads();
    }
    if (t == 0) bsum[blockIdx.x] = s[0];
}

// in-place exclusive scan of counts -> offsets; copy to woff.
// Computes its own block-prefix from the raw bsum array (scanB folded in).
__global__ void scanC_kernel(int* __restrict__ off, const int* __restrict__ bsum,
                             int* __restrict__ woff) {
    __shared__ int sb[NB];
    __shared__ int s[256];
    int t = threadIdx.x;
    if (t < NB) sb[t] = bsum[t];
    __syncthreads();
    int pre = 0, tot = 0;
    int myb = (int)blockIdx.x;
    for (int b = 0; b < NB; b++) {
        int x = sb[b];
        if (b < myb) pre += x;
        tot += x;
    }
    int base = myb * 1024 + t * 4;
    int v[4];
    int tsum = 0;
#pragma unroll
    for (int j = 0; j < 4; j++) {
        int idx = base + j;
        v[j] = (idx < N_NODES) ? off[idx] : 0;
        tsum += v[j];
    }
    s[t] = tsum;
    __syncthreads();
    for (int o = 1; o < 256; o <<= 1) {
        int x = (t >= o) ? s[t - o] : 0;
        __syncthreads();
        s[t] += x;
        __syncthreads();
    }
    int excl = s[t] - tsum + pre;
#pragma unroll
    for (int j = 0; j < 4; j++) {
        int idx = base + j;
        if (idx < N_NODES) {
            off[idx] = excl;
            woff[idx] = excl;
            excl += v[j];
        }
    }
    if (myb == 0 && t == 0) off[N_NODES] = tot;
}

// scatter edges into dst-grouped order; ONE packed 16B record per edge:
// {src, bias(h0,h1) fp16x2, bias(h2,h3) fp16x2, pad}
__global__ void scatter_kernel(const int* __restrict__ src_idx,
                               const int* __restrict__ dst_idx,
                               const float* __restrict__ edge_feat,
                               const float* __restrict__ We,
                               const float* __restrict__ be,
                               int* __restrict__ woff,
                               ix4* __restrict__ prec) {
    int e = blockIdx.x * blockDim.x + threadIdx.x;
    if (e >= N_EDGES) return;
    int d = dst_idx[e];
    int s = src_idx[e];
    const fx4* ep = (const fx4*)(edge_feat + (long)e * 16);
    fx4 e0 = __builtin_nontemporal_load(ep);      // true streaming, 102 MB
    fx4 e1 = __builtin_nontemporal_load(ep + 1);
    fx4 e2 = __builtin_nontemporal_load(ep + 2);
    fx4 e3 = __builtin_nontemporal_load(ep + 3);
    int pos = atomicAdd(&woff[d], 1);
    float bp[4];
#pragma unroll
    for (int h = 0; h < NH; h++) {
        const float4* wp = (const float4*)(We + h * 16);
        float4 w0 = wp[0], w1 = wp[1], w2 = wp[2], w3 = wp[3];
        float acc = be[h];
        acc += e0[0] * w0.x + e0[1] * w0.y + e0[2] * w0.z + e0[3] * w0.w;
        acc += e1[0] * w1.x + e1[1] * w1.y + e1[2] * w1.z + e1[3] * w1.w;
        acc += e2[0] * w2.x + e2[1] * w2.y + e2[2] * w2.z + e2[3] * w2.w;
        acc += e3[0] * w3.x + e3[1] * w3.y + e3[2] * w3.z + e3[3] * w3.w;
        bp[h] = acc;
    }
    __half2 b01 = __halves2half2(__float2half_rn(bp[0]), __float2half_rn(bp[1]));
    __half2 b23 = __halves2half2(__float2half_rn(bp[2]), __float2half_rn(bp[3]));
    ix4 rec;
    rec.x = s;
    rec.y = __builtin_bit_cast(int, b01);
    rec.z = __builtin_bit_cast(int, b23);
    rec.w = 0;
    prec[pos] = rec;
}

// ---- QKV projections via MFMA (fp16 hi/lo split = fp32-accurate) -----------
// A-frag: row=lane&15, k=(lane>>4)*8+j (contiguous from row-major feat).
// B-frag: col=lane&15, same k (contiguous from row-major W: need W[col][k]).
// D: col=lane&15, row=(lane>>4)*4+r.  (verified in R5, absmax unchanged)
// Split precision: x = hi + lo (fp16); D = Ah*Bh + Al*Bh + Ah*Bl, fp32 acc.
// This round: 4 tiles per wave (B packed ONCE per 4 tiles, 16 A-loads of MLP)
// and K+V fused in one wave (shared A fragments from src_feat).
__device__ __forceinline__ void pack2(fx4 a, fx4 b, h8v& hi, h8v& lo) {
#pragma unroll
    for (int j = 0; j < 4; j++) {
        float xa = a[j], xb = b[j];
        _Float16 ha = (_Float16)xa, hb = (_Float16)xb;
        hi[j] = ha;
        hi[j + 4] = hb;
        lo[j] = (_Float16)(xa - (float)ha);
        lo[j + 4] = (_Float16)(xb - (float)hb);
    }
}

#define MFMA6(ACC, AH0, AL0, AH1, AL1, BH0, BL0, BH1, BL1)                      \
    ACC = __builtin_amdgcn_mfma_f32_16x16x32_f16(AH0, BH0, ACC, 0, 0, 0);       \
    ACC = __builtin_amdgcn_mfma_f32_16x16x32_f16(AL0, BH0, ACC, 0, 0, 0);       \
    ACC = __builtin_amdgcn_mfma_f32_16x16x32_f16(AH0, BL0, ACC, 0, 0, 0);       \
    ACC = __builtin_amdgcn_mfma_f32_16x16x32_f16(AH1, BH1, ACC, 0, 0, 0);       \
    ACC = __builtin_amdgcn_mfma_f32_16x16x32_f16(AL1, BH1, ACC, 0, 0, 0);       \
    ACC = __builtin_amdgcn_mfma_f32_16x16x32_f16(AH1, BL1, ACC, 0, 0, 0);

__global__ __launch_bounds__(256) void qkv_kernel(
    const float* __restrict__ dst_feat, const float* __restrict__ src_feat,
    const float* __restrict__ Wq, const float* __restrict__ Wk,
    const float* __restrict__ Wv,
    float* __restrict__ Q, __half* __restrict__ KVh) {
    int lane = threadIdx.x & 63;
    int wid = threadIdx.x >> 6;
    int wave = blockIdx.x * 4 + wid;
    if (wave >= QKV_WAVES) return;
    bool isQ = wave < QKV_GROUPS;
    int tg = isQ ? wave : wave - QKV_GROUPS;
    const float* F = isQ ? dst_feat : src_feat;
    int r16 = lane & 15;
    int kg = lane >> 4;
    // Load + pack A fragments for 4 tiles (clamped; stores guarded by live[])
    h8v Ah0[QKV_TPG], Al0[QKV_TPG], Ah1[QKV_TPG], Al1[QKV_TPG];
    int tbase[QKV_TPG];
    bool live[QKV_TPG];
#pragma unroll
    for (int t = 0; t < QKV_TPG; t++) {
        int tile = tg * QKV_TPG + t;
        live[t] = tile < QKV_TILES;
        if (!live[t]) tile = QKV_TILES - 1;
        tbase[t] = tile * 16;
        const fx4* fr = (const fx4*)(F + (long)(tbase[t] + r16) * 64 + kg * 8);
        fx4 fa = fr[0], fb = fr[1], fc = fr[8], fd = fr[9];
        pack2(fa, fb, Ah0[t], Al0[t]);
        pack2(fc, fd, Ah1[t], Al1[t]);
    }
    if (isQ) {
#pragma unroll
        for (int c = 0; c < 4; c++) {
            const fx4* wr = (const fx4*)(Wq + (long)(c * 16 + r16) * 64 + kg * 8);
            fx4 wa = wr[0], wb = wr[1], wc = wr[8], wd = wr[9];
            h8v Bh0, Bl0, Bh1, Bl1;
            pack2(wa, wb, Bh0, Bl0);
            pack2(wc, wd, Bh1, Bl1);
            int ocol = c * 16 + r16;
#pragma unroll
            for (int t = 0; t < QKV_TPG; t++) {
                fx4 acc = {0.f, 0.f, 0.f, 0.f};
                MFMA6(acc, Ah0[t], Al0[t], Ah1[t], Al1[t], Bh0, Bl0, Bh1, Bl1);
                if (live[t]) {
                    long orow = tbase[t] + kg * 4;
#pragma unroll
                    for (int r = 0; r < 4; r++)
                        Q[(orow + r) * 64 + ocol] = acc[r];
                }
            }
        }
    } else {
        // fused K+V: same A fragments, two B sets
#pragma unroll
        for (int c = 0; c < 4; c++) {
            const fx4* wrk = (const fx4*)(Wk + (long)(c * 16 + r16) * 64 + kg * 8);
            const fx4* wrv = (const fx4*)(Wv + (long)(c * 16 + r16) * 64 + kg * 8);
            fx4 ka = wrk[0], kb = wrk[1], kc = wrk[8], kd = wrk[9];
            fx4 va = wrv[0], vb = wrv[1], vc = wrv[8], vd = wrv[9];
            h8v Kh0, Kl0, Kh1, Kl1, Vh0, Vl0, Vh1, Vl1;
            pack2(ka, kb, Kh0, Kl0);
            pack2(kc, kd, Kh1, Kl1);
            pack2(va, vb, Vh0, Vl0);
            pack2(vc, vd, Vh1, Vl1);
            int ocol = c * 16 + r16;
#pragma unroll
            for (int t = 0; t < QKV_TPG; t++) {
                fx4 acck = {0.f, 0.f, 0.f, 0.f};
                fx4 accv = {0.f, 0.f, 0.f, 0.f};
                MFMA6(acck, Ah0[t], Al0[t], Ah1[t], Al1[t], Kh0, Kl0, Kh1, Kl1);
                MFMA6(accv, Ah0[t], Al0[t], Ah1[t], Al1[t], Vh0, Vl0, Vh1, Vl1);
                if (live[t]) {
                    long orow = tbase[t] + kg * 4;
#pragma unroll
                    for (int r = 0; r < 4; r++) {
                        KVh[(orow + r) * 128 + ocol] = __float2half_rn(acck[r]);
                        KVh[(orow + r) * 128 + 64 + ocol] = __float2half_rn(accv[r]);
                    }
                }
            }
        }
    }
}

// ---- fused score + softmax + aggregate (no max subtraction; scores bounded) -
// Score layout: lane = edge_slot*4 + head. Agg layout: lane = head*16 + dim.
// Writes hv in-place over Q.
// Static 16-wide V gather with SGPR (readlane) src broadcast; pipeline:
// next K-step's prec record and next group's off pair / first record
// prefetched during current compute. Den reduced once per group.
__global__ __launch_bounds__(256) void agg_kernel(
    float* QH, const __half* __restrict__ KVh,
    const int* __restrict__ off, const ix4* __restrict__ prec) {
    int lane = threadIdx.x & 63;
    int wid = threadIdx.x >> 6;
    int h = lane & 3;    // score-layout head
    int es = lane >> 2;  // score-layout edge slot
    int ha = lane >> 4;  // agg-layout head
    int g = blockIdx.x;
    int stride = gridDim.x;
    if (g >= AGG_GROUPS) return;
    int beg = off[g * 4 + wid];
    int end = off[g * 4 + wid + 1];
    ix4 rec0 = {0, 0, 0, 0};
    if (end > beg) {
        int cnt = end - beg;
        int sl = es < cnt ? es : cnt - 1;
        rec0 = prec[beg + sl];
    }
    while (true) {
        int gn = g + stride;
        bool more = gn < AGG_GROUPS;
        int nbeg = 0, nend = 0;
        if (more) {  // issue next group's offsets early; latency hides under compute
            nbeg = off[gn * 4 + wid];
            nend = off[gn * 4 + wid + 1];
        }
        int node = g * 4 + wid;
        const float4* qp = (const float4*)(QH + (long)node * 64 + h * 16);
        float4 q0 = qp[0], q1 = qp[1], q2 = qp[2], q3 = qp[3];
        float den = 0.f, acc = 0.f;
        ix4 rec = rec0;
        for (int b = beg; b < end; b += 16) {
            int bn = b + 16;
            ix4 recn = rec;
            if (bn < end) {  // prefetch next K-step's record
                int c2 = end - bn;
                int sl = es < c2 ? es : c2 - 1;
                recn = prec[bn + sl];
            }
            int s = rec.x;
            unsigned u = (h < 2) ? (unsigned)rec.y : (unsigned)rec.z;
            unsigned hw = (h & 1) ? (u >> 16) : (u & 0xffffu);
            float bias = __half2float(__ushort_as_half((unsigned short)hw));
            // K fragment: 16 halves (32B), loaded as 2 float4
            const float4* kp4 = (const float4*)(KVh + (long)s * 128 + h * 16);
            float4 kr0 = kp4[0], kr1 = kp4[1];
            // independent V-row gathers: src broadcast via readlane -> SGPR
            // base, so each load is scalar-base + lane*2. Clamped slots are
            // cache hits.
            float vv[16];
#pragma unroll
            for (int e = 0; e < 16; e++) {
                int se = __builtin_amdgcn_readlane(s, e * 4);
                vv[e] = __half2float(KVh[(long)se * 128 + 64 + lane]);
            }
            const __half2* kh0 = (const __half2*)&kr0;
            const __half2* kh1 = (const __half2*)&kr1;
            float d0 = 0.f, d1 = 0.f;
            float2 kf;
            kf = __half22float2(kh0[0]); d0 += q0.x * kf.x + q0.y * kf.y;
            kf = __half22float2(kh0[1]); d1 += q0.z * kf.x + q0.w * kf.y;
            kf = __half22float2(kh0[2]); d0 += q1.x * kf.x + q1.y * kf.y;
            kf = __half22float2(kh0[3]); d1 += q1.z * kf.x + q1.w * kf.y;
            kf = __half22float2(kh1[0]); d0 += q2.x * kf.x + q2.y * kf.y;
            kf = __half22float2(kh1[1]); d1 += q2.z * kf.x + q2.w * kf.y;
            kf = __half22float2(kh1[2]); d0 += q3.x * kf.x + q3.y * kf.y;
            kf = __half22float2(kh1[3]); d1 += q3.z * kf.x + q3.w * kf.y;
            float sc = (d0 + d1) * 0.25f + bias;
            bool valid = (b + es) < end;
            float p = valid ? __expf(sc) : 0.f;  // no max: scores bounded ~|10|
            den += p;                             // reduced once after the loop
            float pe[16];
#pragma unroll
            for (int e = 0; e < 16; e++) pe[e] = __shfl(p, e * 4 + ha, 64);
            float a0 = 0.f, a1 = 0.f, a2 = 0.f, a3 = 0.f;
#pragma unroll
            for (int e = 0; e < 16; e += 4) {
                a0 += pe[e] * vv[e];
                a1 += pe[e + 1] * vv[e + 1];
                a2 += pe[e + 2] * vv[e + 2];
                a3 += pe[e + 3] * vv[e + 3];
            }
            acc += (a0 + a1) + (a2 + a3);
            rec = recn;
        }
        if (more && nend > nbeg) {  // prefetch next group's first record
            int cnt = nend - nbeg;
            int sl = es < cnt ? es : cnt - 1;
            rec0 = prec[nbeg + sl];
        }
        den += __shfl_xor(den, 4, 64);
        den += __shfl_xor(den, 8, 64);
        den += __shfl_xor(den, 16, 64);
        den += __shfl_xor(den, 32, 64);
        float denA = __shfl(den, ha, 64);
        float hv = (denA > 0.f) ? acc / denA : 0.f;
        QH[(long)node * 64 + lane] = hv;
        if (!more) break;
        g = gn;
        beg = nbeg;
        end = nend;
    }
}

// ---- output projection via MFMA: out = H @ Wo.T + bo -----------------------
// Same structure as qkv (4 tiles/wave, hi/lo split); bias in accumulator init.
__global__ __launch_bounds__(256) void oproj_kernel(
    const float* __restrict__ H, const float* __restrict__ Wo,
    const float* __restrict__ bo, float* __restrict__ out) {
    int lane = threadIdx.x & 63;
    int wid = threadIdx.x >> 6;
    int wave = blockIdx.x * 4 + wid;
    if (wave >= OP_GROUPS) return;
    int r16 = lane & 15;
    int kg = lane >> 4;
    h8v Ah0[QKV_TPG], Al0[QKV_TPG], Ah1[QKV_TPG], Al1[QKV_TPG];
    int tbase[QKV_TPG];
    bool live[QKV_TPG];
#pragma unroll
    for (int t = 0; t < QKV_TPG; t++) {
        int tile = wave * QKV_TPG + t;
        live[t] = tile < QKV_TILES;
        if (!live[t]) tile = QKV_TILES - 1;
        tbase[t] = tile * 16;
        const fx4* fr = (const fx4*)(H + (long)(tbase[t] + r16) * 64 + kg * 8);
        fx4 fa = fr[0], fb = fr[1], fc = fr[8], fd = fr[9];
        pack2(fa, fb, Ah0[t], Al0[t]);
        pack2(fc, fd, Ah1[t], Al1[t]);
    }
#pragma unroll
    for (int c = 0; c < 4; c++) {
        const fx4* wr = (const fx4*)(Wo + (long)(c * 16 + r16) * 64 + kg * 8);
        fx4 wa = wr[0], wb = wr[1], wc = wr[8], wd = wr[9];
        h8v Bh0, Bl0, Bh1, Bl1;
        pack2(wa, wb, Bh0, Bl0);
        pack2(wc, wd, Bh1, Bl1);
        int ocol = c * 16 + r16;
        float bias = bo[ocol];
#pragma unroll
        for (int t = 0; t < QKV_TPG; t++) {
            fx4 acc = {bias, bias, bias, bias};
            MFMA6(acc, Ah0[t], Al0[t], Ah1[t], Al1[t], Bh0, Bl0, Bh1, Bl1);
            if (live[t]) {
                long orow = tbase[t] + kg * 4;
#pragma unroll
                for (int r = 0; r < 4; r++)
                    out[(orow + r) * 64 + ocol] = acc[r];
            }
        }
    }
}

extern "C" void kernel_launch(void* const* d_in, const int* in_sizes, int n_in,
                              void* d_out, int out_size, void* d_ws, size_t ws_size,
                              hipStream_t stream) {
    const float* src_feat  = (const float*)d_in[0];
    const float* dst_feat  = (const float*)d_in[1];
    const float* edge_feat = (const float*)d_in[2];
    const int*   src_idx   = (const int*)d_in[3];
    const int*   dst_idx   = (const int*)d_in[4];
    const float* Wq        = (const float*)d_in[5];
    const float* Wk        = (const float*)d_in[6];
    const float* Wv        = (const float*)d_in[7];
    const float* We        = (const float*)d_in[8];
    const float* be        = (const float*)d_in[9];
    const float* Wo        = (const float*)d_in[10];
    const float* bo        = (const float*)d_in[11];
    float* out = (float*)d_out;

    // ws layout
    float*  Q    = (float*)d_ws;                          // N*64 f (also hv out)
    __half* KVh  = (__half*)(Q + (size_t)N_NODES * 64);   // N*128 h
    ix4*    prec = (ix4*)(KVh + (size_t)N_NODES * 128);   // E recs (16B)
    int*    off  = (int*)(prec + (size_t)N_EDGES);        // N+1
    int*    woff = off + (N_NODES + 1);                   // N
    int*    bsum = woff + N_NODES;                        // NB

    (void)hipMemsetAsync(off, 0, (N_NODES + 1) * sizeof(int), stream);
    hist_kernel<<<(N_EDGES / 4 + 255) / 256, 256, 0, stream>>>(dst_idx, off);
    scanA_kernel<<<NB, 256, 0, stream>>>(off, bsum);
    scanC_kernel<<<NB, 256, 0, stream>>>(off, bsum, woff);
    scatter_kernel<<<(N_EDGES + 255) / 256, 256, 0, stream>>>(
        src_idx, dst_idx, edge_feat, We, be, woff, prec);
    qkv_kernel<<<(QKV_WAVES + 3) / 4, 256, 0, stream>>>(
        dst_feat, src_feat, Wq, Wk, Wv, Q, KVh);
    agg_kernel<<<2048, 256, 0, stream>>>(Q, KVh, off, prec);
    oproj_kernel<<<(OP_GROUPS + 3) / 4, 256, 0, stream>>>(Q, Wo, bo, out);
}

// Round 7
// 288.837 us; speedup vs baseline: 1.3954x; 1.0009x over previous
//
#include <hip/hip_runtime.h>
#include <hip/hip_fp16.h>
#include <math.h>

#define N_NODES 100000
#define N_EDGES 1600000
#define NH 4
#define HD 16
#define NB 98             // ceil(100000/1024) scan blocks
#define AGG_GROUPS 25000  // N_NODES/4
#define QKV_TILES 6250    // 100000/16 node-tiles
#define QKV_TPG 4         // tiles per wave
#define QKV_GROUPS 1563   // ceil(6250/4)
#define QKV_WAVES (2 * QKV_GROUPS)  // Q-groups + fused-KV-groups
#define OP_GROUPS 1563    // oproj wave-groups (4 tiles each)

typedef float fx4 __attribute__((ext_vector_type(4)));
typedef int   ix4 __attribute__((ext_vector_type(4)));
typedef _Float16 h8v __attribute__((ext_vector_type(8)));

// ---- CSR build -------------------------------------------------------------

// off[] must be zeroed (hipMemsetAsync) before this.
// Saves each edge's within-node arrival rank (the atomic's return value) so
// scatter needs NO atomic: pos = scanned_off[d] + rank[e].
__global__ void hist_kernel(const int* __restrict__ dst_idx, int* __restrict__ off,
                            int* __restrict__ rank) {
    int tid = blockIdx.x * blockDim.x + threadIdx.x;
    int base = tid * 4;
    if (base + 3 < N_EDGES) {
        int4 d = ((const int4*)dst_idx)[tid];  // cached: dst_idx reused by scatter
        int4 r;
        r.x = atomicAdd(&off[d.x], 1);
        r.y = atomicAdd(&off[d.y], 1);
        r.z = atomicAdd(&off[d.z], 1);
        r.w = atomicAdd(&off[d.w], 1);
        ((int4*)rank)[tid] = r;
    } else {
        for (int j = base; j < N_EDGES; j++)
            if (j < N_EDGES) rank[j] = atomicAdd(&off[dst_idx[j]], 1);
    }
}

// per-block sums of 1024-element chunks
__global__ void scanA_kernel(const int* __restrict__ off, int* __restrict__ bsum) {
    __shared__ int s[256];
    int t = threadIdx.x;
    int base = blockIdx.x * 1024 + t * 4;
    int v = 0;
#pragma unroll
    for (int j = 0; j < 4; j++) {
        int idx = base + j;
        if (idx < N_NODES) v += off[idx];
    }
    s[t] = v;
    __syncthreads();
    for (int o = 128; o > 0; o >>= 1) {
        if (t < o) s[t] += s[t + o];
        __syncthreads();
    }
    if (t == 0) bsum[blockIdx.x] = s[0];
}

// in-place exclusive scan of counts -> offsets.
// Computes its own block-prefix from the raw bsum array (scanB folded in).
__global__ void scanC_kernel(int* __restrict__ off, const int* __restrict__ bsum) {
    __shared__ int sb[NB];
    __shared__ int s[256];
    int t = threadIdx.x;
    if (t < NB) sb[t] = bsum[t];
    __syncthreads();
    int pre = 0, tot = 0;
    int myb = (int)blockIdx.x;
    for (int b = 0; b < NB; b++) {
        int x = sb[b];
        if (b < myb) pre += x;
        tot += x;
    }
    int base = myb * 1024 + t * 4;
    int v[4];
    int tsum = 0;
#pragma unroll
    for (int j = 0; j < 4; j++) {
        int idx = base + j;
        v[j] = (idx < N_NODES) ? off[idx] : 0;
        tsum += v[j];
    }
    s[t] = tsum;
    __syncthreads();
    for (int o = 1; o < 256; o <<= 1) {
        int x = (t >= o) ? s[t - o] : 0;
        __syncthreads();
        s[t] += x;
        __syncthreads();
    }
    int excl = s[t] - tsum + pre;
#pragma unroll
    for (int j = 0; j < 4; j++) {
        int idx = base + j;
        if (idx < N_NODES) {
            off[idx] = excl;
            excl += v[j];
        }
    }
    if (myb == 0 && t == 0) off[N_NODES] = tot;
}

// scatter edges into dst-grouped order; ONE packed 16B record per edge:
// {src, bias(h0,h1) fp16x2, bias(h2,h3) fp16x2, pad}
// Atomic-free (rank precomputed in hist); NT store: no L2 line allocation ->
// no read-for-ownership on the random 16B writes.
__global__ void scatter_kernel(const int* __restrict__ src_idx,
                               const int* __restrict__ dst_idx,
                               const int* __restrict__ rank,
                               const float* __restrict__ edge_feat,
                               const float* __restrict__ We,
                               const float* __restrict__ be,
                               const int* __restrict__ off,
                               ix4* __restrict__ prec) {
    int e = blockIdx.x * blockDim.x + threadIdx.x;
    if (e >= N_EDGES) return;
    int d = dst_idx[e];
    int s = src_idx[e];
    int rk = rank[e];
    const fx4* ep = (const fx4*)(edge_feat + (long)e * 16);
    fx4 e0 = __builtin_nontemporal_load(ep);      // true streaming, 102 MB
    fx4 e1 = __builtin_nontemporal_load(ep + 1);
    fx4 e2 = __builtin_nontemporal_load(ep + 2);
    fx4 e3 = __builtin_nontemporal_load(ep + 3);
    int pos = off[d] + rk;
    float bp[4];
#pragma unroll
    for (int h = 0; h < NH; h++) {
        const float4* wp = (const float4*)(We + h * 16);
        float4 w0 = wp[0], w1 = wp[1], w2 = wp[2], w3 = wp[3];
        float acc = be[h];
        acc += e0[0] * w0.x + e0[1] * w0.y + e0[2] * w0.z + e0[3] * w0.w;
        acc += e1[0] * w1.x + e1[1] * w1.y + e1[2] * w1.z + e1[3] * w1.w;
        acc += e2[0] * w2.x + e2[1] * w2.y + e2[2] * w2.z + e2[3] * w2.w;
        acc += e3[0] * w3.x + e3[1] * w3.y + e3[2] * w3.z + e3[3] * w3.w;
        bp[h] = acc;
    }
    __half2 b01 = __halves2half2(__float2half_rn(bp[0]), __float2half_rn(bp[1]));
    __half2 b23 = __halves2half2(__float2half_rn(bp[2]), __float2half_rn(bp[3]));
    ix4 rec;
    rec.x = s;
    rec.y = __builtin_bit_cast(int, b01);
    rec.z = __builtin_bit_cast(int, b23);
    rec.w = 0;
    __builtin_nontemporal_store(rec, &prec[pos]);
}

// ---- QKV projections via MFMA (fp16 hi/lo split = fp32-accurate) -----------
// A-frag: row=lane&15, k=(lane>>4)*8+j (contiguous from row-major feat).
// B-frag: col=lane&15, same k (contiguous from row-major W: need W[col][k]).
// D: col=lane&15, row=(lane>>4)*4+r.  (verified in R5/R6, absmax unchanged)
// Split precision: x = hi + lo (fp16); D = Ah*Bh + Al*Bh + Ah*Bl, fp32 acc.
// 4 tiles per wave (B packed ONCE per 4 tiles); K+V fused in one wave.
__device__ __forceinline__ void pack2(fx4 a, fx4 b, h8v& hi, h8v& lo) {
#pragma unroll
    for (int j = 0; j < 4; j++) {
        float xa = a[j], xb = b[j];
        _Float16 ha = (_Float16)xa, hb = (_Float16)xb;
        hi[j] = ha;
        hi[j + 4] = hb;
        lo[j] = (_Float16)(xa - (float)ha);
        lo[j + 4] = (_Float16)(xb - (float)hb);
    }
}

#define MFMA6(ACC, AH0, AL0, AH1, AL1, BH0, BL0, BH1, BL1)                      \
    ACC = __builtin_amdgcn_mfma_f32_16x16x32_f16(AH0, BH0, ACC, 0, 0, 0);       \
    ACC = __builtin_amdgcn_mfma_f32_16x16x32_f16(AL0, BH0, ACC, 0, 0, 0);       \
    ACC = __builtin_amdgcn_mfma_f32_16x16x32_f16(AH0, BL0, ACC, 0, 0, 0);       \
    ACC = __builtin_amdgcn_mfma_f32_16x16x32_f16(AH1, BH1, ACC, 0, 0, 0);       \
    ACC = __builtin_amdgcn_mfma_f32_16x16x32_f16(AL1, BH1, ACC, 0, 0, 0);       \
    ACC = __builtin_amdgcn_mfma_f32_16x16x32_f16(AH1, BL1, ACC, 0, 0, 0);

__global__ __launch_bounds__(256) void qkv_kernel(
    const float* __restrict__ dst_feat, const float* __restrict__ src_feat,
    const float* __restrict__ Wq, const float* __restrict__ Wk,
    const float* __restrict__ Wv,
    float* __restrict__ Q, __half* __restrict__ KVh) {
    int lane = threadIdx.x & 63;
    int wid = threadIdx.x >> 6;
    int wave = blockIdx.x * 4 + wid;
    if (wave >= QKV_WAVES) return;
    bool isQ = wave < QKV_GROUPS;
    int tg = isQ ? wave : wave - QKV_GROUPS;
    const float* F = isQ ? dst_feat : src_feat;
    int r16 = lane & 15;
    int kg = lane >> 4;
    // Load + pack A fragments for 4 tiles (clamped; stores guarded by live[])
    h8v Ah0[QKV_TPG], Al0[QKV_TPG], Ah1[QKV_TPG], Al1[QKV_TPG];
    int tbase[QKV_TPG];
    bool live[QKV_TPG];
#pragma unroll
    for (int t = 0; t < QKV_TPG; t++) {
        int tile = tg * QKV_TPG + t;
        live[t] = tile < QKV_TILES;
        if (!live[t]) tile = QKV_TILES - 1;
        tbase[t] = tile * 16;
        const fx4* fr = (const fx4*)(F + (long)(tbase[t] + r16) * 64 + kg * 8);
        fx4 fa = fr[0], fb = fr[1], fc = fr[8], fd = fr[9];
        pack2(fa, fb, Ah0[t], Al0[t]);
        pack2(fc, fd, Ah1[t], Al1[t]);
    }
    if (isQ) {
#pragma unroll
        for (int c = 0; c < 4; c++) {
            const fx4* wr = (const fx4*)(Wq + (long)(c * 16 + r16) * 64 + kg * 8);
            fx4 wa = wr[0], wb = wr[1], wc = wr[8], wd = wr[9];
            h8v Bh0, Bl0, Bh1, Bl1;
            pack2(wa, wb, Bh0, Bl0);
            pack2(wc, wd, Bh1, Bl1);
            int ocol = c * 16 + r16;
#pragma unroll
            for (int t = 0; t < QKV_TPG; t++) {
                fx4 acc = {0.f, 0.f, 0.f, 0.f};
                MFMA6(acc, Ah0[t], Al0[t], Ah1[t], Al1[t], Bh0, Bl0, Bh1, Bl1);
                if (live[t]) {
                    long orow = tbase[t] + kg * 4;
#pragma unroll
                    for (int r = 0; r < 4; r++)
                        Q[(orow + r) * 64 + ocol] = acc[r];
                }
            }
        }
    } else {
        // fused K+V: same A fragments, two B sets
#pragma unroll
        for (int c = 0; c < 4; c++) {
            const fx4* wrk = (const fx4*)(Wk + (long)(c * 16 + r16) * 64 + kg * 8);
            const fx4* wrv = (const fx4*)(Wv + (long)(c * 16 + r16) * 64 + kg * 8);
            fx4 ka = wrk[0], kb = wrk[1], kc = wrk[8], kd = wrk[9];
            fx4 va = wrv[0], vb = wrv[1], vc = wrv[8], vd = wrv[9];
            h8v Kh0, Kl0, Kh1, Kl1, Vh0, Vl0, Vh1, Vl1;
            pack2(ka, kb, Kh0, Kl0);
            pack2(kc, kd, Kh1, Kl1);
            pack2(va, vb, Vh0, Vl0);
            pack2(vc, vd, Vh1, Vl1);
            int ocol = c * 16 + r16;
#pragma unroll
            for (int t = 0; t < QKV_TPG; t++) {
                fx4 acck = {0.f, 0.f, 0.f, 0.f};
                fx4 accv = {0.f, 0.f, 0.f, 0.f};
                MFMA6(acck, Ah0[t], Al0[t], Ah1[t], Al1[t], Kh0, Kl0, Kh1, Kl1);
                MFMA6(accv, Ah0[t], Al0[t], Ah1[t], Al1[t], Vh0, Vl0, Vh1, Vl1);
                if (live[t]) {
                    long orow = tbase[t] + kg * 4;
#pragma unroll
                    for (int r = 0; r < 4; r++) {
                        KVh[(orow + r) * 128 + ocol] = __float2half_rn(acck[r]);
                        KVh[(orow + r) * 128 + 64 + ocol] = __float2half_rn(accv[r]);
                    }
                }
            }
        }
    }
}

// ---- fused score + softmax + aggregate (no max subtraction; scores bounded) -
// Score layout: lane = edge_slot*4 + head. Agg layout: lane = head*16 + dim.
// Writes hv in-place over Q.
// Static 16-wide V gather with SGPR (readlane) src broadcast; pipeline:
// next K-step's prec record and next group's off pair / first record
// prefetched during current compute. Den reduced once per group.
__global__ __launch_bounds__(256) void agg_kernel(
    float* QH, const __half* __restrict__ KVh,
    const int* __restrict__ off, const ix4* __restrict__ prec) {
    int lane = threadIdx.x & 63;
    int wid = threadIdx.x >> 6;
    int h = lane & 3;    // score-layout head
    int es = lane >> 2;  // score-layout edge slot
    int ha = lane >> 4;  // agg-layout head
    int g = blockIdx.x;
    int stride = gridDim.x;
    if (g >= AGG_GROUPS) return;
    int beg = off[g * 4 + wid];
    int end = off[g * 4 + wid + 1];
    ix4 rec0 = {0, 0, 0, 0};
    if (end > beg) {
        int cnt = end - beg;
        int sl = es < cnt ? es : cnt - 1;
        rec0 = prec[beg + sl];
    }
    while (true) {
        int gn = g + stride;
        bool more = gn < AGG_GROUPS;
        int nbeg = 0, nend = 0;
        if (more) {  // issue next group's offsets early; latency hides under compute
            nbeg = off[gn * 4 + wid];
            nend = off[gn * 4 + wid + 1];
        }
        int node = g * 4 + wid;
        const float4* qp = (const float4*)(QH + (long)node * 64 + h * 16);
        float4 q0 = qp[0], q1 = qp[1], q2 = qp[2], q3 = qp[3];
        float den = 0.f, acc = 0.f;
        ix4 rec = rec0;
        for (int b = beg; b < end; b += 16) {
            int bn = b + 16;
            ix4 recn = rec;
            if (bn < end) {  // prefetch next K-step's record
                int c2 = end - bn;
                int sl = es < c2 ? es : c2 - 1;
                recn = prec[bn + sl];
            }
            int s = rec.x;
            unsigned u = (h < 2) ? (unsigned)rec.y : (unsigned)rec.z;
            unsigned hw = (h & 1) ? (u >> 16) : (u & 0xffffu);
            float bias = __half2float(__ushort_as_half((unsigned short)hw));
            // K fragment: 16 halves (32B), loaded as 2 float4
            const float4* kp4 = (const float4*)(KVh + (long)s * 128 + h * 16);
            float4 kr0 = kp4[0], kr1 = kp4[1];
            // independent V-row gathers: src broadcast via readlane -> SGPR
            // base, so each load is scalar-base + lane*2. Clamped slots are
            // cache hits.
            float vv[16];
#pragma unroll
            for (int e = 0; e < 16; e++) {
                int se = __builtin_amdgcn_readlane(s, e * 4);
                vv[e] = __half2float(KVh[(long)se * 128 + 64 + lane]);
            }
            const __half2* kh0 = (const __half2*)&kr0;
            const __half2* kh1 = (const __half2*)&kr1;
            float d0 = 0.f, d1 = 0.f;
            float2 kf;
            kf = __half22float2(kh0[0]); d0 += q0.x * kf.x + q0.y * kf.y;
            kf = __half22float2(kh0[1]); d1 += q0.z * kf.x + q0.w * kf.y;
            kf = __half22float2(kh0[2]); d0 += q1.x * kf.x + q1.y * kf.y;
            kf = __half22float2(kh0[3]); d1 += q1.z * kf.x + q1.w * kf.y;
            kf = __half22float2(kh1[0]); d0 += q2.x * kf.x + q2.y * kf.y;
            kf = __half22float2(kh1[1]); d1 += q2.z * kf.x + q2.w * kf.y;
            kf = __half22float2(kh1[2]); d0 += q3.x * kf.x + q3.y * kf.y;
            kf = __half22float2(kh1[3]); d1 += q3.z * kf.x + q3.w * kf.y;
            float sc = (d0 + d1) * 0.25f + bias;
            bool valid = (b + es) < end;
            float p = valid ? __expf(sc) : 0.f;  // no max: scores bounded ~|10|
            den += p;                             // reduced once after the loop
            float pe[16];
#pragma unroll
            for (int e = 0; e < 16; e++) pe[e] = __shfl(p, e * 4 + ha, 64);
            float a0 = 0.f, a1 = 0.f, a2 = 0.f, a3 = 0.f;
#pragma unroll
            for (int e = 0; e < 16; e += 4) {
                a0 += pe[e] * vv[e];
                a1 += pe[e + 1] * vv[e + 1];
                a2 += pe[e + 2] * vv[e + 2];
                a3 += pe[e + 3] * vv[e + 3];
            }
            acc += (a0 + a1) + (a2 + a3);
            rec = recn;
        }
        if (more && nend > nbeg) {  // prefetch next group's first record
            int cnt = nend - nbeg;
            int sl = es < cnt ? es : cnt - 1;
            rec0 = prec[nbeg + sl];
        }
        den += __shfl_xor(den, 4, 64);
        den += __shfl_xor(den, 8, 64);
        den += __shfl_xor(den, 16, 64);
        den += __shfl_xor(den, 32, 64);
        float denA = __shfl(den, ha, 64);
        float hv = (denA > 0.f) ? acc / denA : 0.f;
        QH[(long)node * 64 + lane] = hv;
        if (!more) break;
        g = gn;
        beg = nbeg;
        end = nend;
    }
}

// ---- output projection via MFMA: out = H @ Wo.T + bo -----------------------
// Same structure as qkv (4 tiles/wave, hi/lo split); bias in accumulator init.
__global__ __launch_bounds__(256) void oproj_kernel(
    const float* __restrict__ H, const float* __restrict__ Wo,
    const float* __restrict__ bo, float* __restrict__ out) {
    int lane = threadIdx.x & 63;
    int wid = threadIdx.x >> 6;
    int wave = blockIdx.x * 4 + wid;
    if (wave >= OP_GROUPS) return;
    int r16 = lane & 15;
    int kg = lane >> 4;
    h8v Ah0[QKV_TPG], Al0[QKV_TPG], Ah1[QKV_TPG], Al1[QKV_TPG];
    int tbase[QKV_TPG];
    bool live[QKV_TPG];
#pragma unroll
    for (int t = 0; t < QKV_TPG; t++) {
        int tile = wave * QKV_TPG + t;
        live[t] = tile < QKV_TILES;
        if (!live[t]) tile = QKV_TILES - 1;
        tbase[t] = tile * 16;
        const fx4* fr = (const fx4*)(H + (long)(tbase[t] + r16) * 64 + kg * 8);
        fx4 fa = fr[0], fb = fr[1], fc = fr[8], fd = fr[9];
        pack2(fa, fb, Ah0[t], Al0[t]);
        pack2(fc, fd, Ah1[t], Al1[t]);
    }
#pragma unroll
    for (int c = 0; c < 4; c++) {
        const fx4* wr = (const fx4*)(Wo + (long)(c * 16 + r16) * 64 + kg * 8);
        fx4 wa = wr[0], wb = wr[1], wc = wr[8], wd = wr[9];
        h8v Bh0, Bl0, Bh1, Bl1;
        pack2(wa, wb, Bh0, Bl0);
        pack2(wc, wd, Bh1, Bl1);
        int ocol = c * 16 + r16;
        float bias = bo[ocol];
#pragma unroll
        for (int t = 0; t < QKV_TPG; t++) {
            fx4 acc = {bias, bias, bias, bias};
            MFMA6(acc, Ah0[t], Al0[t], Ah1[t], Al1[t], Bh0, Bl0, Bh1, Bl1);
            if (live[t]) {
                long orow = tbase[t] + kg * 4;
#pragma unroll
                for (int r = 0; r < 4; r++)
                    out[(orow + r) * 64 + ocol] = acc[r];
            }
        }
    }
}

extern "C" void kernel_launch(void* const* d_in, const int* in_sizes, int n_in,
                              void* d_out, int out_size, void* d_ws, size_t ws_size,
                              hipStream_t stream) {
    const float* src_feat  = (const float*)d_in[0];
    const float* dst_feat  = (const float*)d_in[1];
    const float* edge_feat = (const float*)d_in[2];
    const int*   src_idx   = (const int*)d_in[3];
    const int*   dst_idx   = (const int*)d_in[4];
    const float* Wq        = (const float*)d_in[5];
    const float* Wk        = (const float*)d_in[6];
    const float* Wv        = (const float*)d_in[7];
    const float* We        = (const float*)d_in[8];
    const float* be        = (const float*)d_in[9];
    const float* Wo        = (const float*)d_in[10];
    const float* bo        = (const float*)d_in[11];
    float* out = (float*)d_out;

    // ws layout
    float*  Q    = (float*)d_ws;                          // N*64 f (also hv out)
    __half* KVh  = (__half*)(Q + (size_t)N_NODES * 64);   // N*128 h
    ix4*    prec = (ix4*)(KVh + (size_t)N_NODES * 128);   // E recs (16B)
    int*    off  = (int*)(prec + (size_t)N_EDGES);        // N+1
    int*    bsum = off + (N_NODES + 1);                   // NB
    // rank[E] aliases Q's buffer: consumed by scatter BEFORE qkv writes Q.
    int*    rank = (int*)Q;

    (void)hipMemsetAsync(off, 0, (N_NODES + 1) * sizeof(int), stream);
    hist_kernel<<<(N_EDGES / 4 + 255) / 256, 256, 0, stream>>>(dst_idx, off, rank);
    scanA_kernel<<<NB, 256, 0, stream>>>(off, bsum);
    scanC_kernel<<<NB, 256, 0, stream>>>(off, bsum);
    scatter_kernel<<<(N_EDGES + 255) / 256, 256, 0, stream>>>(
        src_idx, dst_idx, rank, edge_feat, We, be, off, prec);
    qkv_kernel<<<(QKV_WAVES + 3) / 4, 256, 0, stream>>>(
        dst_feat, src_feat, Wq, Wk, Wv, Q, KVh);
    agg_kernel<<<2048, 256, 0, stream>>>(Q, KVh, off, prec);
    oproj_kernel<<<(OP_GROUPS + 3) / 4, 256, 0, stream>>>(Q, Wo, bo, out);
}

// Round 8
// 273.087 us; speedup vs baseline: 1.4759x; 1.0577x over previous
//
#include <hip/hip_runtime.h>
#include <hip/hip_fp16.h>
#include <math.h>

#define N_NODES 100000
#define N_EDGES 1600000
#define NH 4
#define HD 16
#define NB 98             // ceil(100000/1024) scan blocks
#define AGG_GROUPS 25000  // N_NODES/4
#define QKV_TILES 6250    // 100000/16 node-tiles
#define QKV_TPG 4         // tiles per wave
#define QKV_GROUPS 1563   // ceil(6250/4)
#define QKV_WAVES (2 * QKV_GROUPS)  // Q-groups + fused-KV-groups
#define OP_GROUPS 1563    // oproj wave-groups (4 tiles each)

typedef float fx4 __attribute__((ext_vector_type(4)));
typedef int   ix4 __attribute__((ext_vector_type(4)));
typedef _Float16 h8v __attribute__((ext_vector_type(8)));

// ---- CSR build -------------------------------------------------------------

// off[] must be zeroed (hipMemsetAsync) before this.
// Saves each edge's within-node arrival rank (the atomic's return value) so
// scatter needs NO atomic: pos = scanned_off[d] + rank[e].
__global__ void hist_kernel(const int* __restrict__ dst_idx, int* __restrict__ off,
                            int* __restrict__ rank) {
    int tid = blockIdx.x * blockDim.x + threadIdx.x;
    int base = tid * 4;
    if (base + 3 < N_EDGES) {
        int4 d = ((const int4*)dst_idx)[tid];  // cached: dst_idx reused by scatter
        int4 r;
        r.x = atomicAdd(&off[d.x], 1);
        r.y = atomicAdd(&off[d.y], 1);
        r.z = atomicAdd(&off[d.z], 1);
        r.w = atomicAdd(&off[d.w], 1);
        ((int4*)rank)[tid] = r;
    } else {
        for (int j = base; j < N_EDGES; j++)
            if (j < N_EDGES) rank[j] = atomicAdd(&off[dst_idx[j]], 1);
    }
}

// per-block sums of 1024-element chunks
__global__ void scanA_kernel(const int* __restrict__ off, int* __restrict__ bsum) {
    __shared__ int s[256];
    int t = threadIdx.x;
    int base = blockIdx.x * 1024 + t * 4;
    int v = 0;
#pragma unroll
    for (int j = 0; j < 4; j++) {
        int idx = base + j;
        if (idx < N_NODES) v += off[idx];
    }
    s[t] = v;
    __syncthreads();
    for (int o = 128; o > 0; o >>= 1) {
        if (t < o) s[t] += s[t + o];
        __syncthreads();
    }
    if (t == 0) bsum[blockIdx.x] = s[0];
}

// in-place exclusive scan of counts -> offsets.
// Computes its own block-prefix from the raw bsum array (scanB folded in).
__global__ void scanC_kernel(int* __restrict__ off, const int* __restrict__ bsum) {
    __shared__ int sb[NB];
    __shared__ int s[256];
    int t = threadIdx.x;
    if (t < NB) sb[t] = bsum[t];
    __syncthreads();
    int pre = 0, tot = 0;
    int myb = (int)blockIdx.x;
    for (int b = 0; b < NB; b++) {
        int x = sb[b];
        if (b < myb) pre += x;
        tot += x;
    }
    int base = myb * 1024 + t * 4;
    int v[4];
    int tsum = 0;
#pragma unroll
    for (int j = 0; j < 4; j++) {
        int idx = base + j;
        v[j] = (idx < N_NODES) ? off[idx] : 0;
        tsum += v[j];
    }
    s[t] = tsum;
    __syncthreads();
    for (int o = 1; o < 256; o <<= 1) {
        int x = (t >= o) ? s[t - o] : 0;
        __syncthreads();
        s[t] += x;
        __syncthreads();
    }
    int excl = s[t] - tsum + pre;
#pragma unroll
    for (int j = 0; j < 4; j++) {
        int idx = base + j;
        if (idx < N_NODES) {
            off[idx] = excl;
            excl += v[j];
        }
    }
    if (myb == 0 && t == 0) off[N_NODES] = tot;
}

// scatter edges into dst-grouped order; ONE packed 16B record per edge:
// {src, bias(h0,h1) fp16x2, bias(h2,h3) fp16x2, pad}
// Atomic-free (rank precomputed in hist). PLAIN cached store for prec:
// R7 showed NT stores push prec to HBM and add ~10% to agg's rec-chain
// latency (consumer pays for the producer's NT hint).
__global__ void scatter_kernel(const int* __restrict__ src_idx,
                               const int* __restrict__ dst_idx,
                               const int* __restrict__ rank,
                               const float* __restrict__ edge_feat,
                               const float* __restrict__ We,
                               const float* __restrict__ be,
                               const int* __restrict__ off,
                               ix4* __restrict__ prec) {
    int e = blockIdx.x * blockDim.x + threadIdx.x;
    if (e >= N_EDGES) return;
    int d = dst_idx[e];
    int s = src_idx[e];
    int rk = rank[e];
    const fx4* ep = (const fx4*)(edge_feat + (long)e * 16);
    fx4 e0 = __builtin_nontemporal_load(ep);      // true streaming, 102 MB
    fx4 e1 = __builtin_nontemporal_load(ep + 1);
    fx4 e2 = __builtin_nontemporal_load(ep + 2);
    fx4 e3 = __builtin_nontemporal_load(ep + 3);
    int pos = off[d] + rk;
    float bp[4];
#pragma unroll
    for (int h = 0; h < NH; h++) {
        const float4* wp = (const float4*)(We + h * 16);
        float4 w0 = wp[0], w1 = wp[1], w2 = wp[2], w3 = wp[3];
        float acc = be[h];
        acc += e0[0] * w0.x + e0[1] * w0.y + e0[2] * w0.z + e0[3] * w0.w;
        acc += e1[0] * w1.x + e1[1] * w1.y + e1[2] * w1.z + e1[3] * w1.w;
        acc += e2[0] * w2.x + e2[1] * w2.y + e2[2] * w2.z + e2[3] * w2.w;
        acc += e3[0] * w3.x + e3[1] * w3.y + e3[2] * w3.z + e3[3] * w3.w;
        bp[h] = acc;
    }
    __half2 b01 = __halves2half2(__float2half_rn(bp[0]), __float2half_rn(bp[1]));
    __half2 b23 = __halves2half2(__float2half_rn(bp[2]), __float2half_rn(bp[3]));
    ix4 rec;
    rec.x = s;
    rec.y = __builtin_bit_cast(int, b01);
    rec.z = __builtin_bit_cast(int, b23);
    rec.w = 0;
    prec[pos] = rec;
}

// ---- QKV projections via MFMA (fp16 hi/lo split = fp32-accurate) -----------
// A-frag: row=lane&15, k=(lane>>4)*8+j (contiguous from row-major feat).
// B-frag: col=lane&15, same k (contiguous from row-major W: need W[col][k]).
// D: col=lane&15, row=(lane>>4)*4+r.  (verified in R5/R6, absmax unchanged)
// Split precision: x = hi + lo (fp16); D = Ah*Bh + Al*Bh + Ah*Bl, fp32 acc.
// 4 tiles per wave (B packed ONCE per 4 tiles); K+V fused in one wave.
__device__ __forceinline__ void pack2(fx4 a, fx4 b, h8v& hi, h8v& lo) {
#pragma unroll
    for (int j = 0; j < 4; j++) {
        float xa = a[j], xb = b[j];
        _Float16 ha = (_Float16)xa, hb = (_Float16)xb;
        hi[j] = ha;
        hi[j + 4] = hb;
        lo[j] = (_Float16)(xa - (float)ha);
        lo[j + 4] = (_Float16)(xb - (float)hb);
    }
}

#define MFMA6(ACC, AH0, AL0, AH1, AL1, BH0, BL0, BH1, BL1)                      \
    ACC = __builtin_amdgcn_mfma_f32_16x16x32_f16(AH0, BH0, ACC, 0, 0, 0);       \
    ACC = __builtin_amdgcn_mfma_f32_16x16x32_f16(AL0, BH0, ACC, 0, 0, 0);       \
    ACC = __builtin_amdgcn_mfma_f32_16x16x32_f16(AH0, BL0, ACC, 0, 0, 0);       \
    ACC = __builtin_amdgcn_mfma_f32_16x16x32_f16(AH1, BH1, ACC, 0, 0, 0);       \
    ACC = __builtin_amdgcn_mfma_f32_16x16x32_f16(AL1, BH1, ACC, 0, 0, 0);       \
    ACC = __builtin_amdgcn_mfma_f32_16x16x32_f16(AH1, BL1, ACC, 0, 0, 0);

__global__ __launch_bounds__(256) void qkv_kernel(
    const float* __restrict__ dst_feat, const float* __restrict__ src_feat,
    const float* __restrict__ Wq, const float* __restrict__ Wk,
    const float* __restrict__ Wv,
    float* __restrict__ Q, __half* __restrict__ KVh) {
    int lane = threadIdx.x & 63;
    int wid = threadIdx.x >> 6;
    int wave = blockIdx.x * 4 + wid;
    if (wave >= QKV_WAVES) return;
    bool isQ = wave < QKV_GROUPS;
    int tg = isQ ? wave : wave - QKV_GROUPS;
    const float* F = isQ ? dst_feat : src_feat;
    int r16 = lane & 15;
    int kg = lane >> 4;
    // Load + pack A fragments for 4 tiles (clamped; stores guarded by live[])
    h8v Ah0[QKV_TPG], Al0[QKV_TPG], Ah1[QKV_TPG], Al1[QKV_TPG];
    int tbase[QKV_TPG];
    bool live[QKV_TPG];
#pragma unroll
    for (int t = 0; t < QKV_TPG; t++) {
        int tile = tg * QKV_TPG + t;
        live[t] = tile < QKV_TILES;
        if (!live[t]) tile = QKV_TILES - 1;
        tbase[t] = tile * 16;
        const fx4* fr = (const fx4*)(F + (long)(tbase[t] + r16) * 64 + kg * 8);
        fx4 fa = fr[0], fb = fr[1], fc = fr[8], fd = fr[9];
        pack2(fa, fb, Ah0[t], Al0[t]);
        pack2(fc, fd, Ah1[t], Al1[t]);
    }
    if (isQ) {
#pragma unroll
        for (int c = 0; c < 4; c++) {
            const fx4* wr = (const fx4*)(Wq + (long)(c * 16 + r16) * 64 + kg * 8);
            fx4 wa = wr[0], wb = wr[1], wc = wr[8], wd = wr[9];
            h8v Bh0, Bl0, Bh1, Bl1;
            pack2(wa, wb, Bh0, Bl0);
            pack2(wc, wd, Bh1, Bl1);
            int ocol = c * 16 + r16;
#pragma unroll
            for (int t = 0; t < QKV_TPG; t++) {
                fx4 acc = {0.f, 0.f, 0.f, 0.f};
                MFMA6(acc, Ah0[t], Al0[t], Ah1[t], Al1[t], Bh0, Bl0, Bh1, Bl1);
                if (live[t]) {
                    long orow = tbase[t] + kg * 4;
#pragma unroll
                    for (int r = 0; r < 4; r++)
                        Q[(orow + r) * 64 + ocol] = acc[r];
                }
            }
        }
    } else {
        // fused K+V: same A fragments, two B sets
#pragma unroll
        for (int c = 0; c < 4; c++) {
            const fx4* wrk = (const fx4*)(Wk + (long)(c * 16 + r16) * 64 + kg * 8);
            const fx4* wrv = (const fx4*)(Wv + (long)(c * 16 + r16) * 64 + kg * 8);
            fx4 ka = wrk[0], kb = wrk[1], kc = wrk[8], kd = wrk[9];
            fx4 va = wrv[0], vb = wrv[1], vc = wrv[8], vd = wrv[9];
            h8v Kh0, Kl0, Kh1, Kl1, Vh0, Vl0, Vh1, Vl1;
            pack2(ka, kb, Kh0, Kl0);
            pack2(kc, kd, Kh1, Kl1);
            pack2(va, vb, Vh0, Vl0);
            pack2(vc, vd, Vh1, Vl1);
            int ocol = c * 16 + r16;
#pragma unroll
            for (int t = 0; t < QKV_TPG; t++) {
                fx4 acck = {0.f, 0.f, 0.f, 0.f};
                fx4 accv = {0.f, 0.f, 0.f, 0.f};
                MFMA6(acck, Ah0[t], Al0[t], Ah1[t], Al1[t], Kh0, Kl0, Kh1, Kl1);
                MFMA6(accv, Ah0[t], Al0[t], Ah1[t], Al1[t], Vh0, Vl0, Vh1, Vl1);
                if (live[t]) {
                    long orow = tbase[t] + kg * 4;
#pragma unroll
                    for (int r = 0; r < 4; r++) {
                        KVh[(orow + r) * 128 + ocol] = __float2half_rn(acck[r]);
                        KVh[(orow + r) * 128 + 64 + ocol] = __float2half_rn(accv[r]);
                    }
                }
            }
        }
    }
}

// ---- fused score + softmax + aggregate (no max subtraction; scores bounded) -
// Score layout: lane = edge_slot*4 + head. Agg layout: lane = head*16 + dim.
// Writes hv in-place over Q.
// Static 16-wide V gather with SGPR (readlane) src broadcast; pipeline:
// next K-step's prec record and next group's off pair / first record
// prefetched during current compute. Den reduced once per group.
__global__ __launch_bounds__(256) void agg_kernel(
    float* QH, const __half* __restrict__ KVh,
    const int* __restrict__ off, const ix4* __restrict__ prec) {
    int lane = threadIdx.x & 63;
    int wid = threadIdx.x >> 6;
    int h = lane & 3;    // score-layout head
    int es = lane >> 2;  // score-layout edge slot
    int ha = lane >> 4;  // agg-layout head
    int g = blockIdx.x;
    int stride = gridDim.x;
    if (g >= AGG_GROUPS) return;
    int beg = off[g * 4 + wid];
    int end = off[g * 4 + wid + 1];
    ix4 rec0 = {0, 0, 0, 0};
    if (end > beg) {
        int cnt = end - beg;
        int sl = es < cnt ? es : cnt - 1;
        rec0 = prec[beg + sl];
    }
    while (true) {
        int gn = g + stride;
        bool more = gn < AGG_GROUPS;
        int nbeg = 0, nend = 0;
        if (more) {  // issue next group's offsets early; latency hides under compute
            nbeg = off[gn * 4 + wid];
            nend = off[gn * 4 + wid + 1];
        }
        int node = g * 4 + wid;
        const float4* qp = (const float4*)(QH + (long)node * 64 + h * 16);
        float4 q0 = qp[0], q1 = qp[1], q2 = qp[2], q3 = qp[3];
        float den = 0.f, acc = 0.f;
        ix4 rec = rec0;
        for (int b = beg; b < end; b += 16) {
            int bn = b + 16;
            ix4 recn = rec;
            if (bn < end) {  // prefetch next K-step's record
                int c2 = end - bn;
                int sl = es < c2 ? es : c2 - 1;
                recn = prec[bn + sl];
            }
            int s = rec.x;
            unsigned u = (h < 2) ? (unsigned)rec.y : (unsigned)rec.z;
            unsigned hw = (h & 1) ? (u >> 16) : (u & 0xffffu);
            float bias = __half2float(__ushort_as_half((unsigned short)hw));
            // K fragment: 16 halves (32B), loaded as 2 float4
            const float4* kp4 = (const float4*)(KVh + (long)s * 128 + h * 16);
            float4 kr0 = kp4[0], kr1 = kp4[1];
            // independent V-row gathers: src broadcast via readlane -> SGPR
            // base, so each load is scalar-base + lane*2. Clamped slots are
            // cache hits.
            float vv[16];
#pragma unroll
            for (int e = 0; e < 16; e++) {
                int se = __builtin_amdgcn_readlane(s, e * 4);
                vv[e] = __half2float(KVh[(long)se * 128 + 64 + lane]);
            }
            const __half2* kh0 = (const __half2*)&kr0;
            const __half2* kh1 = (const __half2*)&kr1;
            float d0 = 0.f, d1 = 0.f;
            float2 kf;
            kf = __half22float2(kh0[0]); d0 += q0.x * kf.x + q0.y * kf.y;
            kf = __half22float2(kh0[1]); d1 += q0.z * kf.x + q0.w * kf.y;
            kf = __half22float2(kh0[2]); d0 += q1.x * kf.x + q1.y * kf.y;
            kf = __half22float2(kh0[3]); d1 += q1.z * kf.x + q1.w * kf.y;
            kf = __half22float2(kh1[0]); d0 += q2.x * kf.x + q2.y * kf.y;
            kf = __half22float2(kh1[1]); d1 += q2.z * kf.x + q2.w * kf.y;
            kf = __half22float2(kh1[2]); d0 += q3.x * kf.x + q3.y * kf.y;
            kf = __half22float2(kh1[3]); d1 += q3.z * kf.x + q3.w * kf.y;
            float sc = (d0 + d1) * 0.25f + bias;
            bool valid = (b + es) < end;
            float p = valid ? __expf(sc) : 0.f;  // no max: scores bounded ~|10|
            den += p;                             // reduced once after the loop
            float pe[16];
#pragma unroll
            for (int e = 0; e < 16; e++) pe[e] = __shfl(p, e * 4 + ha, 64);
            float a0 = 0.f, a1 = 0.f, a2 = 0.f, a3 = 0.f;
#pragma unroll
            for (int e = 0; e < 16; e += 4) {
                a0 += pe[e] * vv[e];
                a1 += pe[e + 1] * vv[e + 1];
                a2 += pe[e + 2] * vv[e + 2];
                a3 += pe[e + 3] * vv[e + 3];
            }
            acc += (a0 + a1) + (a2 + a3);
            rec = recn;
        }
        if (more && nend > nbeg) {  // prefetch next group's first record
            int cnt = nend - nbeg;
            int sl = es < cnt ? es : cnt - 1;
            rec0 = prec[nbeg + sl];
        }
        den += __shfl_xor(den, 4, 64);
        den += __shfl_xor(den, 8, 64);
        den += __shfl_xor(den, 16, 64);
        den += __shfl_xor(den, 32, 64);
        float denA = __shfl(den, ha, 64);
        float hv = (denA > 0.f) ? acc / denA : 0.f;
        QH[(long)node * 64 + lane] = hv;
        if (!more) break;
        g = gn;
        beg = nbeg;
        end = nend;
    }
}

// ---- output projection via MFMA: out = H @ Wo.T + bo -----------------------
// Same structure as qkv (4 tiles/wave, hi/lo split); bias in accumulator init.
__global__ __launch_bounds__(256) void oproj_kernel(
    const float* __restrict__ H, const float* __restrict__ Wo,
    const float* __restrict__ bo, float* __restrict__ out) {
    int lane = threadIdx.x & 63;
    int wid = threadIdx.x >> 6;
    int wave = blockIdx.x * 4 + wid;
    if (wave >= OP_GROUPS) return;
    int r16 = lane & 15;
    int kg = lane >> 4;
    h8v Ah0[QKV_TPG], Al0[QKV_TPG], Ah1[QKV_TPG], Al1[QKV_TPG];
    int tbase[QKV_TPG];
    bool live[QKV_TPG];
#pragma unroll
    for (int t = 0; t < QKV_TPG; t++) {
        int tile = wave * QKV_TPG + t;
        live[t] = tile < QKV_TILES;
        if (!live[t]) tile = QKV_TILES - 1;
        tbase[t] = tile * 16;
        const fx4* fr = (const fx4*)(H + (long)(tbase[t] + r16) * 64 + kg * 8);
        fx4 fa = fr[0], fb = fr[1], fc = fr[8], fd = fr[9];
        pack2(fa, fb, Ah0[t], Al0[t]);
        pack2(fc, fd, Ah1[t], Al1[t]);
    }
#pragma unroll
    for (int c = 0; c < 4; c++) {
        const fx4* wr = (const fx4*)(Wo + (long)(c * 16 + r16) * 64 + kg * 8);
        fx4 wa = wr[0], wb = wr[1], wc = wr[8], wd = wr[9];
        h8v Bh0, Bl0, Bh1, Bl1;
        pack2(wa, wb, Bh0, Bl0);
        pack2(wc, wd, Bh1, Bl1);
        int ocol = c * 16 + r16;
        float bias = bo[ocol];
#pragma unroll
        for (int t = 0; t < QKV_TPG; t++) {
            fx4 acc = {bias, bias, bias, bias};
            MFMA6(acc, Ah0[t], Al0[t], Ah1[t], Al1[t], Bh0, Bl0, Bh1, Bl1);
            if (live[t]) {
                long orow = tbase[t] + kg * 4;
#pragma unroll
                for (int r = 0; r < 4; r++)
                    out[(orow + r) * 64 + ocol] = acc[r];
            }
        }
    }
}

extern "C" void kernel_launch(void* const* d_in, const int* in_sizes, int n_in,
                              void* d_out, int out_size, void* d_ws, size_t ws_size,
                              hipStream_t stream) {
    const float* src_feat  = (const float*)d_in[0];
    const float* dst_feat  = (const float*)d_in[1];
    const float* edge_feat = (const float*)d_in[2];
    const int*   src_idx   = (const int*)d_in[3];
    const int*   dst_idx   = (const int*)d_in[4];
    const float* Wq        = (const float*)d_in[5];
    const float* Wk        = (const float*)d_in[6];
    const float* Wv        = (const float*)d_in[7];
    const float* We        = (const float*)d_in[8];
    const float* be        = (const float*)d_in[9];
    const float* Wo        = (const float*)d_in[10];
    const float* bo        = (const float*)d_in[11];
    float* out = (float*)d_out;

    // ws layout
    float*  Q    = (float*)d_ws;                          // N*64 f (also hv out)
    __half* KVh  = (__half*)(Q + (size_t)N_NODES * 64);   // N*128 h
    ix4*    prec = (ix4*)(KVh + (size_t)N_NODES * 128);   // E recs (16B)
    int*    off  = (int*)(prec + (size_t)N_EDGES);        // N+1
    int*    bsum = off + (N_NODES + 1);                   // NB
    // rank[E] aliases Q's buffer: consumed by scatter BEFORE qkv writes Q.
    int*    rank = (int*)Q;

    (void)hipMemsetAsync(off, 0, (N_NODES + 1) * sizeof(int), stream);
    hist_kernel<<<(N_EDGES / 4 + 255) / 256, 256, 0, stream>>>(dst_idx, off, rank);
    scanA_kernel<<<NB, 256, 0, stream>>>(off, bsum);
    scanC_kernel<<<NB, 256, 0, stream>>>(off, bsum);
    scatter_kernel<<<(N_EDGES + 255) / 256, 256, 0, stream>>>(
        src_idx, dst_idx, rank, edge_feat, We, be, off, prec);
    qkv_kernel<<<(QKV_WAVES + 3) / 4, 256, 0, stream>>>(
        dst_feat, src_feat, Wq, Wk, Wv, Q, KVh);
    agg_kernel<<<2048, 256, 0, stream>>>(Q, KVh, off, prec);
    oproj_kernel<<<(OP_GROUPS + 3) / 4, 256, 0, stream>>>(Q, Wo, bo, out);
}

// Round 9
// 269.267 us; speedup vs baseline: 1.4968x; 1.0142x over previous
//
#include <hip/hip_runtime.h>
#include <hip/hip_fp16.h>
#include <math.h>

#define N_NODES 100000
#define N_EDGES 1600000
#define NH 4
#define HD 16
#define NB 98             // ceil(100000/1024) scan blocks
#define AGG_GROUPS 25000  // N_NODES/4
#define AGG_BLOCKS 3125   // 8 groups per block exactly (no ragged tail)
#define QKV_TILES 6250    // 100000/16 node-tiles
#define QKV_TPG 4         // tiles per wave
#define QKV_GROUPS 1563   // ceil(6250/4)
#define QKV_WAVES (2 * QKV_GROUPS)  // Q-groups + fused-KV-groups
#define OP_GROUPS 1563    // oproj wave-groups (4 tiles each)

typedef float fx4 __attribute__((ext_vector_type(4)));
typedef int   ix4 __attribute__((ext_vector_type(4)));
typedef _Float16 h8v __attribute__((ext_vector_type(8)));

// ---- CSR build -------------------------------------------------------------

// off[] must be zeroed (hipMemsetAsync) before this.
// Saves each edge's within-node arrival rank (the atomic's return value) so
// scatter needs NO atomic: pos = scanned_off[d] + rank[e].
__global__ void hist_kernel(const int* __restrict__ dst_idx, int* __restrict__ off,
                            int* __restrict__ rank) {
    int tid = blockIdx.x * blockDim.x + threadIdx.x;
    int base = tid * 4;
    if (base + 3 < N_EDGES) {
        int4 d = ((const int4*)dst_idx)[tid];  // cached: dst_idx reused by scatter
        int4 r;
        r.x = atomicAdd(&off[d.x], 1);
        r.y = atomicAdd(&off[d.y], 1);
        r.z = atomicAdd(&off[d.z], 1);
        r.w = atomicAdd(&off[d.w], 1);
        ((int4*)rank)[tid] = r;
    } else {
        for (int j = base; j < N_EDGES; j++)
            if (j < N_EDGES) rank[j] = atomicAdd(&off[dst_idx[j]], 1);
    }
}

// per-block sums of 1024-element chunks
__global__ void scanA_kernel(const int* __restrict__ off, int* __restrict__ bsum) {
    __shared__ int s[256];
    int t = threadIdx.x;
    int base = blockIdx.x * 1024 + t * 4;
    int v = 0;
#pragma unroll
    for (int j = 0; j < 4; j++) {
        int idx = base + j;
        if (idx < N_NODES) v += off[idx];
    }
    s[t] = v;
    __syncthreads();
    for (int o = 128; o > 0; o >>= 1) {
        if (t < o) s[t] += s[t + o];
        __syncthreads();
    }
    if (t == 0) bsum[blockIdx.x] = s[0];
}

// in-place exclusive scan of counts -> offsets.
// Computes its own block-prefix from the raw bsum array (scanB folded in).
__global__ void scanC_kernel(int* __restrict__ off, const int* __restrict__ bsum) {
    __shared__ int sb[NB];
    __shared__ int s[256];
    int t = threadIdx.x;
    if (t < NB) sb[t] = bsum[t];
    __syncthreads();
    int pre = 0, tot = 0;
    int myb = (int)blockIdx.x;
    for (int b = 0; b < NB; b++) {
        int x = sb[b];
        if (b < myb) pre += x;
        tot += x;
    }
    int base = myb * 1024 + t * 4;
    int v[4];
    int tsum = 0;
#pragma unroll
    for (int j = 0; j < 4; j++) {
        int idx = base + j;
        v[j] = (idx < N_NODES) ? off[idx] : 0;
        tsum += v[j];
    }
    s[t] = tsum;
    __syncthreads();
    for (int o = 1; o < 256; o <<= 1) {
        int x = (t >= o) ? s[t - o] : 0;
        __syncthreads();
        s[t] += x;
        __syncthreads();
    }
    int excl = s[t] - tsum + pre;
#pragma unroll
    for (int j = 0; j < 4; j++) {
        int idx = base + j;
        if (idx < N_NODES) {
            off[idx] = excl;
            excl += v[j];
        }
    }
    if (myb == 0 && t == 0) off[N_NODES] = tot;
}

// scatter edges into dst-grouped order; ONE packed 16B record per edge:
// {src, bias(h0,h1) fp16x2, bias(h2,h3) fp16x2, pad}
// Atomic-free (rank precomputed in hist). PLAIN cached store for prec
// (R7: NT store pushed prec to HBM and cost agg ~10%).
__global__ void scatter_kernel(const int* __restrict__ src_idx,
                               const int* __restrict__ dst_idx,
                               const int* __restrict__ rank,
                               const float* __restrict__ edge_feat,
                               const float* __restrict__ We,
                               const float* __restrict__ be,
                               const int* __restrict__ off,
                               ix4* __restrict__ prec) {
    int e = blockIdx.x * blockDim.x + threadIdx.x;
    if (e >= N_EDGES) return;
    int d = dst_idx[e];
    int s = src_idx[e];
    int rk = rank[e];
    const fx4* ep = (const fx4*)(edge_feat + (long)e * 16);
    fx4 e0 = __builtin_nontemporal_load(ep);      // true streaming, 102 MB
    fx4 e1 = __builtin_nontemporal_load(ep + 1);
    fx4 e2 = __builtin_nontemporal_load(ep + 2);
    fx4 e3 = __builtin_nontemporal_load(ep + 3);
    int pos = off[d] + rk;
    float bp[4];
#pragma unroll
    for (int h = 0; h < NH; h++) {
        const float4* wp = (const float4*)(We + h * 16);
        float4 w0 = wp[0], w1 = wp[1], w2 = wp[2], w3 = wp[3];
        float acc = be[h];
        acc += e0[0] * w0.x + e0[1] * w0.y + e0[2] * w0.z + e0[3] * w0.w;
        acc += e1[0] * w1.x + e1[1] * w1.y + e1[2] * w1.z + e1[3] * w1.w;
        acc += e2[0] * w2.x + e2[1] * w2.y + e2[2] * w2.z + e2[3] * w2.w;
        acc += e3[0] * w3.x + e3[1] * w3.y + e3[2] * w3.z + e3[3] * w3.w;
        bp[h] = acc;
    }
    __half2 b01 = __halves2half2(__float2half_rn(bp[0]), __float2half_rn(bp[1]));
    __half2 b23 = __halves2half2(__float2half_rn(bp[2]), __float2half_rn(bp[3]));
    ix4 rec;
    rec.x = s;
    rec.y = __builtin_bit_cast(int, b01);
    rec.z = __builtin_bit_cast(int, b23);
    rec.w = 0;
    prec[pos] = rec;
}

// ---- QKV projections via MFMA (fp16 hi/lo split = fp32-accurate) -----------
// A-frag: row=lane&15, k=(lane>>4)*8+j (contiguous from row-major feat).
// B-frag: col=lane&15, same k (contiguous from row-major W: need W[col][k]).
// D: col=lane&15, row=(lane>>4)*4+r.  (verified in R5/R6, absmax unchanged)
// Split precision: x = hi + lo (fp16); D = Ah*Bh + Al*Bh + Ah*Bl, fp32 acc.
// 4 tiles per wave (B packed ONCE per 4 tiles); K+V fused in one wave.
__device__ __forceinline__ void pack2(fx4 a, fx4 b, h8v& hi, h8v& lo) {
#pragma unroll
    for (int j = 0; j < 4; j++) {
        float xa = a[j], xb = b[j];
        _Float16 ha = (_Float16)xa, hb = (_Float16)xb;
        hi[j] = ha;
        hi[j + 4] = hb;
        lo[j] = (_Float16)(xa - (float)ha);
        lo[j + 4] = (_Float16)(xb - (float)hb);
    }
}

#define MFMA6(ACC, AH0, AL0, AH1, AL1, BH0, BL0, BH1, BL1)                      \
    ACC = __builtin_amdgcn_mfma_f32_16x16x32_f16(AH0, BH0, ACC, 0, 0, 0);       \
    ACC = __builtin_amdgcn_mfma_f32_16x16x32_f16(AL0, BH0, ACC, 0, 0, 0);       \
    ACC = __builtin_amdgcn_mfma_f32_16x16x32_f16(AH0, BL0, ACC, 0, 0, 0);       \
    ACC = __builtin_amdgcn_mfma_f32_16x16x32_f16(AH1, BH1, ACC, 0, 0, 0);       \
    ACC = __builtin_amdgcn_mfma_f32_16x16x32_f16(AL1, BH1, ACC, 0, 0, 0);       \
    ACC = __builtin_amdgcn_mfma_f32_16x16x32_f16(AH1, BL1, ACC, 0, 0, 0);

__global__ __launch_bounds__(256) void qkv_kernel(
    const float* __restrict__ dst_feat, const float* __restrict__ src_feat,
    const float* __restrict__ Wq, const float* __restrict__ Wk,
    const float* __restrict__ Wv,
    float* __restrict__ Q, __half* __restrict__ KVh) {
    int lane = threadIdx.x & 63;
    int wid = threadIdx.x >> 6;
    int wave = blockIdx.x * 4 + wid;
    if (wave >= QKV_WAVES) return;
    bool isQ = wave < QKV_GROUPS;
    int tg = isQ ? wave : wave - QKV_GROUPS;
    const float* F = isQ ? dst_feat : src_feat;
    int r16 = lane & 15;
    int kg = lane >> 4;
    // Load + pack A fragments for 4 tiles (clamped; stores guarded by live[])
    h8v Ah0[QKV_TPG], Al0[QKV_TPG], Ah1[QKV_TPG], Al1[QKV_TPG];
    int tbase[QKV_TPG];
    bool live[QKV_TPG];
#pragma unroll
    for (int t = 0; t < QKV_TPG; t++) {
        int tile = tg * QKV_TPG + t;
        live[t] = tile < QKV_TILES;
        if (!live[t]) tile = QKV_TILES - 1;
        tbase[t] = tile * 16;
        const fx4* fr = (const fx4*)(F + (long)(tbase[t] + r16) * 64 + kg * 8);
        fx4 fa = fr[0], fb = fr[1], fc = fr[8], fd = fr[9];
        pack2(fa, fb, Ah0[t], Al0[t]);
        pack2(fc, fd, Ah1[t], Al1[t]);
    }
    if (isQ) {
#pragma unroll
        for (int c = 0; c < 4; c++) {
            const fx4* wr = (const fx4*)(Wq + (long)(c * 16 + r16) * 64 + kg * 8);
            fx4 wa = wr[0], wb = wr[1], wc = wr[8], wd = wr[9];
            h8v Bh0, Bl0, Bh1, Bl1;
            pack2(wa, wb, Bh0, Bl0);
            pack2(wc, wd, Bh1, Bl1);
            int ocol = c * 16 + r16;
#pragma unroll
            for (int t = 0; t < QKV_TPG; t++) {
                fx4 acc = {0.f, 0.f, 0.f, 0.f};
                MFMA6(acc, Ah0[t], Al0[t], Ah1[t], Al1[t], Bh0, Bl0, Bh1, Bl1);
                if (live[t]) {
                    long orow = tbase[t] + kg * 4;
#pragma unroll
                    for (int r = 0; r < 4; r++)
                        Q[(orow + r) * 64 + ocol] = acc[r];
                }
            }
        }
    } else {
        // fused K+V: same A fragments, two B sets
#pragma unroll
        for (int c = 0; c < 4; c++) {
            const fx4* wrk = (const fx4*)(Wk + (long)(c * 16 + r16) * 64 + kg * 8);
            const fx4* wrv = (const fx4*)(Wv + (long)(c * 16 + r16) * 64 + kg * 8);
            fx4 ka = wrk[0], kb = wrk[1], kc = wrk[8], kd = wrk[9];
            fx4 va = wrv[0], vb = wrv[1], vc = wrv[8], vd = wrv[9];
            h8v Kh0, Kl0, Kh1, Kl1, Vh0, Vl0, Vh1, Vl1;
            pack2(ka, kb, Kh0, Kl0);
            pack2(kc, kd, Kh1, Kl1);
            pack2(va, vb, Vh0, Vl0);
            pack2(vc, vd, Vh1, Vl1);
            int ocol = c * 16 + r16;
#pragma unroll
            for (int t = 0; t < QKV_TPG; t++) {
                fx4 acck = {0.f, 0.f, 0.f, 0.f};
                fx4 accv = {0.f, 0.f, 0.f, 0.f};
                MFMA6(acck, Ah0[t], Al0[t], Ah1[t], Al1[t], Kh0, Kl0, Kh1, Kl1);
                MFMA6(accv, Ah0[t], Al0[t], Ah1[t], Al1[t], Vh0, Vl0, Vh1, Vl1);
                if (live[t]) {
                    long orow = tbase[t] + kg * 4;
#pragma unroll
                    for (int r = 0; r < 4; r++) {
                        KVh[(orow + r) * 128 + ocol] = __float2half_rn(acck[r]);
                        KVh[(orow + r) * 128 + 64 + ocol] = __float2half_rn(accv[r]);
                    }
                }
            }
        }
    }
}

// ---- fused score + softmax + aggregate (no max subtraction; scores bounded) -
// Score layout: lane = edge_slot*4 + head. Agg layout: lane = head*16 + dim.
// Writes hv in-place over Q.
// This round's agg changes (traffic is compulsory; attack VALU+latency):
//  - V gathers via uniform SGPR row base (readlane) + lane*2 voffset, issued
//    BEFORE the K-dot so their latency hides under it.
//  - fp16 operands consumed via float*(float)half patterns -> v_fma_mix
//    (no separate cvt instructions; numerics identical).
//  - p broadcast via per-wave LDS row + immediate-offset reads (replaces 16
//    ds_bpermute + their per-e address math; reads are broadcasts, 0 conflicts)
//  - grid 3125 blocks: exactly 8 groups per block, no ragged tail.
__global__ __launch_bounds__(256) void agg_kernel(
    float* QH, const __half* __restrict__ KVh,
    const int* __restrict__ off, const ix4* __restrict__ prec) {
    __shared__ float plds[4][64];
    int lane = threadIdx.x & 63;
    int wid = threadIdx.x >> 6;
    int h = lane & 3;    // score-layout head
    int es = lane >> 2;  // score-layout edge slot
    int ha = lane >> 4;  // agg-layout head
    int g = blockIdx.x;
    int stride = gridDim.x;
    if (g >= AGG_GROUPS) return;
    int beg = off[g * 4 + wid];
    int end = off[g * 4 + wid + 1];
    ix4 rec0 = {0, 0, 0, 0};
    if (end > beg) {
        int cnt = end - beg;
        int sl = es < cnt ? es : cnt - 1;
        rec0 = prec[beg + sl];
    }
    while (true) {
        int gn = g + stride;
        bool more = gn < AGG_GROUPS;
        int nbeg = 0, nend = 0;
        if (more) {  // issue next group's offsets early; latency hides under compute
            nbeg = off[gn * 4 + wid];
            nend = off[gn * 4 + wid + 1];
        }
        int node = g * 4 + wid;
        const float4* qp = (const float4*)(QH + (long)node * 64 + h * 16);
        float4 q0 = qp[0], q1 = qp[1], q2 = qp[2], q3 = qp[3];
        float den = 0.f, acc = 0.f;
        ix4 rec = rec0;
        for (int b = beg; b < end; b += 16) {
            int bn = b + 16;
            ix4 recn = rec;
            if (bn < end) {  // prefetch next K-step's record
                int c2 = end - bn;
                int sl = es < c2 ? es : c2 - 1;
                recn = prec[bn + sl];
            }
            int s = rec.x;
            // V gathers FIRST: uniform (SGPR) row base per e, voffset = lane*2.
            // Latency overlaps the K-dot below. Clamped slots are cache hits.
            __half vv[16];
#pragma unroll
            for (int e = 0; e < 16; e++) {
                int se = __builtin_amdgcn_readlane(s, e * 4);
                const __half* rowp = KVh + (long)se * 128 + 64;
                vv[e] = rowp[lane];
            }
            unsigned u = (h < 2) ? (unsigned)rec.y : (unsigned)rec.z;
            unsigned hw = (h & 1) ? (u >> 16) : (u & 0xffffu);
            float bias = __half2float(__ushort_as_half((unsigned short)hw));
            // K fragment: 16 halves (32B), loaded as 2 float4
            const float4* kp4 = (const float4*)(KVh + (long)s * 128 + h * 16);
            float4 kr0 = kp4[0], kr1 = kp4[1];
            const __half* kh  = (const __half*)&kr0;
            const __half* kh2 = (const __half*)&kr1;
            float d0, d1;
            d0  = q0.x * (float)kh[0];   d1  = q0.y * (float)kh[1];
            d0 += q0.z * (float)kh[2];   d1 += q0.w * (float)kh[3];
            d0 += q1.x * (float)kh[4];   d1 += q1.y * (float)kh[5];
            d0 += q1.z * (float)kh[6];   d1 += q1.w * (float)kh[7];
            d0 += q2.x * (float)kh2[0];  d1 += q2.y * (float)kh2[1];
            d0 += q2.z * (float)kh2[2];  d1 += q2.w * (float)kh2[3];
            d0 += q3.x * (float)kh2[4];  d1 += q3.y * (float)kh2[5];
            d0 += q3.z * (float)kh2[6];  d1 += q3.w * (float)kh2[7];
            float sc = (d0 + d1) * 0.25f + bias;
            bool valid = (b + es) < end;
            float p = valid ? __expf(sc) : 0.f;  // no max: scores bounded ~|10|
            den += p;                             // reduced once after the loop
            // p broadcast: wave-private LDS row, immediate-offset reads
            plds[wid][lane] = p;
            asm volatile("s_waitcnt lgkmcnt(0)" ::: "memory");
            float a0 = 0.f, a1 = 0.f, a2 = 0.f, a3 = 0.f;
#pragma unroll
            for (int e = 0; e < 16; e += 4) {
                a0 += plds[wid][(e + 0) * 4 + ha] * (float)vv[e + 0];
                a1 += plds[wid][(e + 1) * 4 + ha] * (float)vv[e + 1];
                a2 += plds[wid][(e + 2) * 4 + ha] * (float)vv[e + 2];
                a3 += plds[wid][(e + 3) * 4 + ha] * (float)vv[e + 3];
            }
            acc += (a0 + a1) + (a2 + a3);
            rec = recn;
        }
        if (more && nend > nbeg) {  // prefetch next group's first record
            int cnt = nend - nbeg;
            int sl = es < cnt ? es : cnt - 1;
            rec0 = prec[nbeg + sl];
        }
        den += __shfl_xor(den, 4, 64);
        den += __shfl_xor(den, 8, 64);
        den += __shfl_xor(den, 16, 64);
        den += __shfl_xor(den, 32, 64);
        float denA = __shfl(den, ha, 64);
        float hv = (denA > 0.f) ? acc / denA : 0.f;
        QH[(long)node * 64 + lane] = hv;
        if (!more) break;
        g = gn;
        beg = nbeg;
        end = nend;
    }
}

// ---- output projection via MFMA: out = H @ Wo.T + bo -----------------------
// Same structure as qkv (4 tiles/wave, hi/lo split); bias in accumulator init.
__global__ __launch_bounds__(256) void oproj_kernel(
    const float* __restrict__ H, const float* __restrict__ Wo,
    const float* __restrict__ bo, float* __restrict__ out) {
    int lane = threadIdx.x & 63;
    int wid = threadIdx.x >> 6;
    int wave = blockIdx.x * 4 + wid;
    if (wave >= OP_GROUPS) return;
    int r16 = lane & 15;
    int kg = lane >> 4;
    h8v Ah0[QKV_TPG], Al0[QKV_TPG], Ah1[QKV_TPG], Al1[QKV_TPG];
    int tbase[QKV_TPG];
    bool live[QKV_TPG];
#pragma unroll
    for (int t = 0; t < QKV_TPG; t++) {
        int tile = wave * QKV_TPG + t;
        live[t] = tile < QKV_TILES;
        if (!live[t]) tile = QKV_TILES - 1;
        tbase[t] = tile * 16;
        const fx4* fr = (const fx4*)(H + (long)(tbase[t] + r16) * 64 + kg * 8);
        fx4 fa = fr[0], fb = fr[1], fc = fr[8], fd = fr[9];
        pack2(fa, fb, Ah0[t], Al0[t]);
        pack2(fc, fd, Ah1[t], Al1[t]);
    }
#pragma unroll
    for (int c = 0; c < 4; c++) {
        const fx4* wr = (const fx4*)(Wo + (long)(c * 16 + r16) * 64 + kg * 8);
        fx4 wa = wr[0], wb = wr[1], wc = wr[8], wd = wr[9];
        h8v Bh0, Bl0, Bh1, Bl1;
        pack2(wa, wb, Bh0, Bl0);
        pack2(wc, wd, Bh1, Bl1);
        int ocol = c * 16 + r16;
        float bias = bo[ocol];
#pragma unroll
        for (int t = 0; t < QKV_TPG; t++) {
            fx4 acc = {bias, bias, bias, bias};
            MFMA6(acc, Ah0[t], Al0[t], Ah1[t], Al1[t], Bh0, Bl0, Bh1, Bl1);
            if (live[t]) {
                long orow = tbase[t] + kg * 4;
#pragma unroll
                for (int r = 0; r < 4; r++)
                    out[(orow + r) * 64 + ocol] = acc[r];
            }
        }
    }
}

extern "C" void kernel_launch(void* const* d_in, const int* in_sizes, int n_in,
                              void* d_out, int out_size, void* d_ws, size_t ws_size,
                              hipStream_t stream) {
    const float* src_feat  = (const float*)d_in[0];
    const float* dst_feat  = (const float*)d_in[1];
    const float* edge_feat = (const float*)d_in[2];
    const int*   src_idx   = (const int*)d_in[3];
    const int*   dst_idx   = (const int*)d_in[4];
    const float* Wq        = (const float*)d_in[5];
    const float* Wk        = (const float*)d_in[6];
    const float* Wv        = (const float*)d_in[7];
    const float* We        = (const float*)d_in[8];
    const float* be        = (const float*)d_in[9];
    const float* Wo        = (const float*)d_in[10];
    const float* bo        = (const float*)d_in[11];
    float* out = (float*)d_out;

    // ws layout
    float*  Q    = (float*)d_ws;                          // N*64 f (also hv out)
    __half* KVh  = (__half*)(Q + (size_t)N_NODES * 64);   // N*128 h
    ix4*    prec = (ix4*)(KVh + (size_t)N_NODES * 128);   // E recs (16B)
    int*    off  = (int*)(prec + (size_t)N_EDGES);        // N+1
    int*    bsum = off + (N_NODES + 1);                   // NB
    // rank[E] aliases Q's buffer: consumed by scatter BEFORE qkv writes Q.
    int*    rank = (int*)Q;

    (void)hipMemsetAsync(off, 0, (N_NODES + 1) * sizeof(int), stream);
    hist_kernel<<<(N_EDGES / 4 + 255) / 256, 256, 0, stream>>>(dst_idx, off, rank);
    scanA_kernel<<<NB, 256, 0, stream>>>(off, bsum);
    scanC_kernel<<<NB, 256, 0, stream>>>(off, bsum);
    scatter_kernel<<<(N_EDGES + 255) / 256, 256, 0, stream>>>(
        src_idx, dst_idx, rank, edge_feat, We, be, off, prec);
    qkv_kernel<<<(QKV_WAVES + 3) / 4, 256, 0, stream>>>(
        dst_feat, src_feat, Wq, Wk, Wv, Q, KVh);
    agg_kernel<<<AGG_BLOCKS, 256, 0, stream>>>(Q, KVh, off, prec);
    oproj_kernel<<<(OP_GROUPS + 3) / 4, 256, 0, stream>>>(Q, Wo, bo, out);
}